// Round 9
// baseline (271.239 us; speedup 1.0000x reference)
//
#include <hip/hip_runtime.h>
#include <math.h>

// ---------------------------------------------------------------------------
// CODA block on MI355X, fp32. 12 dispatches.
// F on truncated 64x33 grid via one fused per-image 2D DFT; scores via
// Parseval in mode space; A-mix spatial; Pm-only inverse transform fused with
// z assembly + raw row-DFT of z (affine applied later); m1/stats2 closed-form.
// ---------------------------------------------------------------------------

#define EPSV 1e-5f
#define PI2 6.283185307179586f

typedef float2 cf;

__device__ __forceinline__ cf cmul(cf a, cf b){ return make_float2(a.x*b.x - a.y*b.y, a.x*b.y + a.y*b.x); }
__device__ __forceinline__ cf ldc(const float* p){ return make_float2(p[0], p[1]); }
__device__ __forceinline__ void stc(float* p, cf v){ p[0]=v.x; p[1]=v.y; }

__device__ __forceinline__ void init_tw(cf* tw, int N, float dir){
  for (int j = threadIdx.x; j < N; j += blockDim.x){
    float s, c; sincosf(dir * PI2 * (float)j / (float)N, &s, &c);
    tw[j] = make_float2(c, s);
  }
}

__device__ void breduce2(float& a, float& b){
  __shared__ float sha[16], shb[16];
  for (int off = 32; off > 0; off >>= 1){
    a += __shfl_down(a, off, 64);
    b += __shfl_down(b, off, 64);
  }
  int w = threadIdx.x >> 6, lane = threadIdx.x & 63;
  int nw = (blockDim.x + 63) >> 6;
  if (lane == 0){ sha[w] = a; shb[w] = b; }
  __syncthreads();
  if (threadIdx.x == 0){
    for (int i = 1; i < nw; ++i){ a += sha[i]; b += shb[i]; }
    sha[0] = a; shb[0] = b;
  }
  __syncthreads();
  a = sha[0]; b = shb[0];
  __syncthreads();
}

// ---- spectral attention helpers ------------------------------------------
__device__ __forceinline__ cf kq_mode(const float* w, int o, int kh, int kw){
  if (kw < 16){
    if (kh < 16)  return ldc(w + ((o*16+kh)*16+kw)*2);
    if (kh >= 48) return ldc(w + (((32+o)*16+(kh-48))*16+kw)*2);
  }
  return make_float2(0.f,0.f);
}

// fused: blocks 0..31 = gamma (per head), 32..95 = per-image inorm coeffs
__global__ __launch_bounds__(256) void k_gamma_xstats(
                      const float* __restrict__ wQ, const float* __restrict__ wQs,
                      const float* __restrict__ bQs,
                      const float* __restrict__ wK, const float* __restrict__ wKs,
                      const float* __restrict__ bKs,
                      const float* __restrict__ x, const float* __restrict__ ng,
                      const float* __restrict__ nb,
                      float* __restrict__ gam, float* __restrict__ gcons,
                      float* __restrict__ stats, float* __restrict__ normAB){
  if (blockIdx.x >= 32){
    int n = blockIdx.x - 32;
    const float* im = x + n*16384;
    float s=0.f, s2=0.f;
    for (int i=threadIdx.x;i<16384;i+=256){ float v=im[i]; s+=v; s2=fmaf(v,v,s2); }
    breduce2(s,s2);
    if (threadIdx.x==0){
      float m = s*(1.f/16384.f), var = s2*(1.f/16384.f)-m*m;
      float A = rsqrtf(var+EPSV)*ng[0];
      normAB[n*2]=A; normAB[n*2+1]=nb[0]-m*A;
    }
    return;
  }
  int o = blockIdx.x;
  if (o==0){ for (int i=threadIdx.x;i<640;i+=256) stats[i]=0.f; }
  float sQ=wQs[o], sK=wKs[o];
  for (int m = threadIdx.x; m < 2112; m += 256){
    int kh = m/33, kw = m-kh*33;
    cf g;
    if (kw == 0){
      int mh = (64-kh)&63;
      cf qp = kq_mode(wQ,o,kh,0);  qp.x += sQ;
      cf qm = kq_mode(wQ,o,mh,0);  qm.x += sQ;
      cf qt = make_float2(0.5f*(qp.x+qm.x), 0.5f*(qp.y-qm.y));
      cf kp = kq_mode(wK,o,kh,0);  kp.x += sK;
      cf km = kq_mode(wK,o,mh,0);  km.x += sK;
      cf kt = make_float2(0.5f*(kp.x+km.x), 0.5f*(kp.y-km.y));
      g = make_float2(64.f*(qt.x*kt.x + qt.y*kt.y), 64.f*(qt.y*kt.x - qt.x*kt.y));
    } else if (kw == 32){
      g = make_float2(64.f*sQ*sK, 0.f);
    } else {
      cf q = kq_mode(wQ,o,kh,kw); q.x += sQ;
      cf k = kq_mode(wK,o,kh,kw); k.x += sK;
      g = make_float2(128.f*(q.x*k.x + q.y*k.y), 128.f*(q.y*k.x - q.x*k.y));
    }
    stc(gam + (o*2112+m)*2, g);
  }
  if (threadIdx.x == 0){
    float qt0 = sQ + kq_mode(wQ,o,0,0).x;
    float kt0 = sK + kq_mode(wK,o,0,0).x;
    gcons[o]    = 64.f*bKs[o]*qt0;
    gcons[32+o] = 64.f*bQs[o]*kt0;
    gcons[64+o] = 64.f*bQs[o]*bKs[o];
  }
}

// fused forward 2D truncated DFT per image: inorm(x) -> F[64][33]; 64 blocks
__global__ __launch_bounds__(1024) void k_fwd2d(const float* __restrict__ x, const float* __restrict__ normAB,
                                                float* __restrict__ F){
  __shared__ float zb[16384];
  __shared__ cf Crow[4224];   // [h][kw], stride 33
  __shared__ cf tw[128];
  init_tw(tw, 128, -1.f);
  int n = blockIdx.x;
  float A = normAB[n*2], Bc = normAB[n*2+1];
  for (int i=threadIdx.x;i<16384;i+=1024) zb[i] = fmaf(x[n*16384+i], A, Bc);
  __syncthreads();
  for (int i=threadIdx.x;i<8192;i+=1024){
    int h=i>>6, w=i&63;
    float a=zb[h*128+w], b=zb[h*128+w+64];
    zb[h*128+w]=a+b; zb[h*128+w+64]=a-b;
  }
  __syncthreads();
  for (int i=threadIdx.x;i<4224;i+=1024){
    int h=i/33, kw=i-h*33;
    int sel = (kw&1)? 64 : 0;
    float re=0.f, im=0.f; int idx=0;
    for (int w=0;w<64;++w){
      float v=zb[h*128+sel+w]; cf t=tw[idx];
      re=fmaf(v,t.x,re); im=fmaf(v,t.y,im);
      idx=(idx+kw)&127;
    }
    Crow[i] = make_float2(re*(1.f/16384.f), im*(1.f/16384.f));
  }
  __syncthreads();
  for (int i=threadIdx.x;i<2112;i+=1024){
    int h=i/33, kw=i-h*33;
    cf a=Crow[h*33+kw], b=Crow[(h+64)*33+kw];
    Crow[h*33+kw]      = make_float2(a.x+b.x, a.y+b.y);
    Crow[(h+64)*33+kw] = make_float2(a.x-b.x, a.y-b.y);
  }
  __syncthreads();
  for (int i=threadIdx.x;i<2112;i+=1024){
    int r=i/33, kw=i-r*33;
    int R = (r<32)? r : r+64;
    int sel = (r&1)? 64 : 0;
    float re=0.f, im=0.f; int idx=0;
    for (int j=0;j<64;++j){
      cf v=Crow[(sel+j)*33+kw]; cf t=tw[idx];
      re = fmaf(v.x,t.x,re); re = fmaf(-v.y,t.y,re);
      im = fmaf(v.x,t.y,im); im = fmaf(v.y,t.x,im);
      idx=(idx+R)&127;
    }
    stc(F + ((n*64+r)*33+kw)*2, make_float2(re,im));
  }
}

// scoreP partials; grid (32 mk, 2 b, 8 og); 4 heads share one 66-mode E tile
__global__ __launch_bounds__(256) void k_score(const float* __restrict__ F, const float* __restrict__ gam,
                                               float* __restrict__ scoreP){
  __shared__ float2 Esh[66][33];
  __shared__ float2 gsh[4][66];
  int mk = blockIdx.x, b = blockIdx.y, og = blockIdx.z;
  int m0 = mk*66;
  int t = threadIdx.x >> 3, s4 = (threadIdx.x & 7) << 2;
  for (int i = threadIdx.x; i < 2112; i += 256){
    int tt = i/66, j = i - tt*66;
    int m = m0 + j;
    int kh = m/33, kw = m - kh*33;
    const float* Fb = F + (b*32+tt)*4224;
    float2 v;
    if (kw < 32) v = *(const float2*)(Fb + (kh*33+kw)*2);
    else {
      int mh = (64-kh)&63;
      float2 a = *(const float2*)(Fb + (kh*33+32)*2);
      float2 c = *(const float2*)(Fb + (mh*33+32)*2);
      v = make_float2(0.5f*(a.x+c.x), 0.5f*(a.y-c.y));
    }
    Esh[j][tt] = v;
  }
  for (int i = threadIdx.x; i < 264; i += 256){
    int ol = i/66, j = i - ol*66;
    gsh[ol][j] = *(const float2*)(gam + ((og*4+ol)*2112 + m0 + j)*2);
  }
  __syncthreads();
  float acc[4][4];
  #pragma unroll
  for (int a=0;a<4;++a) for (int k=0;k<4;++k) acc[a][k]=0.f;
  #pragma unroll 2
  for (int j=0;j<66;++j){
    float2 et = Esh[j][t];
    float2 e0 = Esh[j][s4+0];
    float2 e1 = Esh[j][s4+1];
    float2 e2 = Esh[j][s4+2];
    float2 e3 = Esh[j][s4+3];
    #pragma unroll
    for (int ol=0;ol<4;++ol){
      float2 g = gsh[ol][j];
      float a  = g.x*et.x - g.y*et.y;
      float bb = g.x*et.y + g.y*et.x;
      acc[ol][0] = fmaf(a,e0.x,fmaf(bb,e0.y,acc[ol][0]));
      acc[ol][1] = fmaf(a,e1.x,fmaf(bb,e1.y,acc[ol][1]));
      acc[ol][2] = fmaf(a,e2.x,fmaf(bb,e2.y,acc[ol][2]));
      acc[ol][3] = fmaf(a,e3.x,fmaf(bb,e3.y,acc[ol][3]));
    }
  }
  #pragma unroll
  for (int ol=0;ol<4;++ol){
    int o = og*4+ol;
    float* sp = scoreP + (((mk*2+b)*32+o)*32 + t)*32 + s4;
    sp[0]=acc[ol][0]; sp[1]=acc[ol][1]; sp[2]=acc[ol][2]; sp[3]=acc[ol][3];
  }
}

// sum 32 partials + DC-linear terms, softmax over s -> attn
__global__ __launch_bounds__(1024) void k_softmax(float* __restrict__ attn, const float* __restrict__ F,
                                                const float* __restrict__ gcons, const float* __restrict__ scoreP){
  __shared__ float Ssh[32][33];
  int b = blockIdx.x, o = blockIdx.y;
  int t = threadIdx.x >> 5, s = threadIdx.x & 31;
  float c0=gcons[o], c1=gcons[32+o], c2=gcons[64+o];
  float sc = c0*F[(b*32+t)*4224] + c1*F[(b*32+s)*4224] + c2;
  #pragma unroll 8
  for (int p=0;p<32;++p) sc += scoreP[(((p*2+b)*32+o)*32 + t)*32 + s];
  Ssh[t][s] = sc;
  __syncthreads();
  float mx = -1e30f;
  for (int ss=0;ss<32;++ss) mx = fmaxf(mx, Ssh[t][ss]);
  float e = expf(sc - mx);
  __syncthreads();
  Ssh[t][s] = e;
  __syncthreads();
  float sum = 0.f;
  for (int ss=0;ss<32;++ss) sum += Ssh[t][ss];
  attn[(b*32+o)*1024 + t*32 + s] = e/sum;
}

__device__ __forceinline__ cf wcV_col0(const float* wV, int o, int fr){
  if (fr < 16)  return ldc(wV + ((o*16+fr)*16)*2);
  if (fr >= 112) return ldc(wV + (((32+o)*16+(fr-112))*16)*2);
  return make_float2(0.f,0.f);
}

// Pm[b,t,mh,kw] = sum_o d[o,m] * sum_s attn[b,o,t,s]*F[bs,m]; grid (2,64,4)
__global__ __launch_bounds__(256) void k_pmode(const float* __restrict__ F, const float* __restrict__ attn,
                        const float* __restrict__ wV, const float* __restrict__ wVs,
                        const float* __restrict__ wP, const float* __restrict__ wPs,
                        float* __restrict__ Pm){
  __shared__ float att[32][8][32];
  __shared__ cf Fsh[32][32];
  __shared__ cf dsh[32][32];
  int b = blockIdx.x, mh = blockIdx.y, tg = blockIdx.z;
  int fr = mh<32 ? mh : mh+64;
  int half = (mh>=32)?1:0, mr = mh&31;
  for (int i=threadIdx.x; i<8192; i+=256){
    int o = i>>8, r = i&255;
    att[o][r>>5][r&31] = attn[(b*32+o)*1024 + tg*256 + r];
  }
  for (int i=threadIdx.x; i<1024; i+=256){
    int s=i>>5, kw=i&31;
    Fsh[s][kw] = ldc(F + (((b*32+s)*64+mh)*33+kw)*2);
  }
  for (int i=threadIdx.x; i<1024; i+=256){
    int o=i>>5, kw=i&31;
    cf wp = ldc(wP + (((half*32+o)*32+mr)*32+kw)*2);
    cf bP = make_float2(wPs[o]+wp.x, wp.y);
    cf aV = make_float2(wVs[o], 0.f);
    if (kw==0){
      cf w1 = wcV_col0(wV,o,fr);
      cf w2 = wcV_col0(wV,o,(128-fr)&127);
      aV.x += 0.5f*(w1.x + w2.x);
      aV.y += 0.5f*(w1.y - w2.y);
    } else if (kw<16){
      if (fr<16){ cf wv=ldc(wV + ((o*16+fr)*16+kw)*2); aV.x+=wv.x; aV.y+=wv.y; }
      else if (fr>=112){ cf wv=ldc(wV + (((32+o)*16+(fr-112))*16+kw)*2); aV.x+=wv.x; aV.y+=wv.y; }
    }
    cf c = cmul(bP, aV);
    c.x -= wPs[o]*wVs[o];
    dsh[o][kw]=c;
  }
  __syncthreads();
  int tl = threadIdx.x>>5, kw = threadIdx.x&31;
  float ax=0.f, ay=0.f;
  for (int o=0;o<32;++o){
    float er=0.f, ei=0.f;
    #pragma unroll
    for (int s4=0;s4<32;s4+=4){
      float4 a4 = *(const float4*)&att[o][tl][s4];
      cf f0=Fsh[s4][kw], f1=Fsh[s4+1][kw], f2=Fsh[s4+2][kw], f3=Fsh[s4+3][kw];
      er=fmaf(a4.x,f0.x,er); ei=fmaf(a4.x,f0.y,ei);
      er=fmaf(a4.y,f1.x,er); ei=fmaf(a4.y,f1.y,ei);
      er=fmaf(a4.z,f2.x,er); ei=fmaf(a4.z,f2.y,ei);
      er=fmaf(a4.w,f3.x,er); ei=fmaf(a4.w,f3.y,ei);
    }
    cf d = dsh[o][kw];
    ax += d.x*er - d.y*ei;
    ay += d.x*ei + d.y*er;
  }
  int t = tg*8+tl;
  stc(Pm + ((b*32+t)*2048 + mh*32+kw)*2, make_float2(ax,ay));
}

// z = spatial A-mix of x + irfft2(Pm) + consts; stats; ALSO raw row-DFT of z
// -> Tm (kw 0..31, scale 1/16384, no an-affine). grid (64, 8 hb)
__global__ __launch_bounds__(256) void k_zmix(const float* __restrict__ x, const float* __restrict__ Pm,
                        const float* __restrict__ attn, const float* __restrict__ normAB,
                        const float* __restrict__ wVs, const float* __restrict__ wPs,
                        const float* __restrict__ wP, const float* __restrict__ bPs,
                        const float* __restrict__ bVs,
                        float* __restrict__ z, float* __restrict__ stats,
                        float* __restrict__ Tm){
  __shared__ cf Pmsh[64][33];
  __shared__ cf PmAsh[16][33];
  __shared__ float zrows[16][128];
  __shared__ float Mrow[32];
  __shared__ float cpart[33];
  __shared__ float consts;
  __shared__ cf tw[128];
  init_tw(tw, 128, 1.f);
  int n = blockIdx.x, b = n>>5, t = n&31, hb = blockIdx.y*8;
  for (int i=threadIdx.x;i<2048;i+=256)
    Pmsh[i>>5][i&31] = ldc(Pm + (n*2048 + i)*2);
  if (threadIdx.x < 32){
    int s = threadIdx.x;
    float a=0.f;
    for (int o=0;o<32;++o) a = fmaf(attn[(b*32+o)*1024 + t*32 + s], wVs[o]*wPs[o], a);
    float AxS = normAB[(b*32+s)*2], BcS = normAB[(b*32+s)*2+1];
    Mrow[s] = fmaf(a, AxS, (s==t)?1.f:0.f);
    cpart[s] = a*BcS;
  } else if (threadIdx.x == 32){
    float dcx = bPs[0];
    for (int o=0;o<32;++o){
      cf wp = ldc(wP + (o*1024)*2);
      dcx += (wPs[o]+wp.x)*bVs[o];
    }
    cpart[32] = dcx;
  }
  __syncthreads();
  if (threadIdx.x == 0){
    float c=0.f;
    for (int i=0;i<33;++i) c += cpart[i];
    consts = c;
  }
  {
    int bl = threadIdx.x>>5, kw = threadIdx.x&31;
    int h = hb + bl;
    float ser=0.f, sei=0.f, sor=0.f, soi=0.f;
    int s2h = (2*h)&127;
    int idx = 0;
    for (int khi=0;khi<32;khi+=2){
      cf v=Pmsh[khi][kw]; cf tt=tw[idx];
      ser += v.x*tt.x - v.y*tt.y; sei += v.x*tt.y + v.y*tt.x;
      idx=(idx+s2h)&127;
    }
    idx = (96*h)&127;
    for (int khi=32;khi<64;khi+=2){
      cf v=Pmsh[khi][kw]; cf tt=tw[idx];
      ser += v.x*tt.x - v.y*tt.y; sei += v.x*tt.y + v.y*tt.x;
      idx=(idx+s2h)&127;
    }
    idx = h&127;
    for (int khi=1;khi<32;khi+=2){
      cf v=Pmsh[khi][kw]; cf tt=tw[idx];
      sor += v.x*tt.x - v.y*tt.y; soi += v.x*tt.y + v.y*tt.x;
      idx=(idx+s2h)&127;
    }
    idx = (97*h)&127;
    for (int khi=33;khi<64;khi+=2){
      cf v=Pmsh[khi][kw]; cf tt=tw[idx];
      sor += v.x*tt.x - v.y*tt.y; soi += v.x*tt.y + v.y*tt.x;
      idx=(idx+s2h)&127;
    }
    PmAsh[bl][kw]   = make_float2(ser+sor, sei+soi);
    PmAsh[8+bl][kw] = make_float2(ser-sor, sei-soi);
  }
  __syncthreads();
  float cst = consts;
  float s1=0.f, s2=0.f;
  const float* xb = x + b*32*16384;
  {
    int hl = threadIdx.x>>4, wg = threadIdx.x&15;
    int w0 = wg*4;
    int gh = (hl<8)? hb+hl : hb+(hl-8)+64;
    int off = gh*128;
    float Se[4], So[4];
    #pragma unroll
    for (int j=0;j<4;++j){
      int w = w0+j;
      int s2w = (2*w)&127;
      float se=0.f, so=0.f;
      int idx=0;
      for (int kwp=0;kwp<16;++kwp){
        cf v = PmAsh[hl][2*kwp]; cf tt=tw[idx];
        float term = v.x*tt.x - v.y*tt.y;
        se += (kwp? 2.f:1.f)*term;
        idx=(idx+s2w)&127;
      }
      idx = w&127;
      for (int kwp=0;kwp<16;++kwp){
        cf v = PmAsh[hl][2*kwp+1]; cf tt=tw[idx];
        so += 2.f*(v.x*tt.x - v.y*tt.y);
        idx=(idx+s2w)&127;
      }
      Se[j]=se; So[j]=so;
    }
    float mixa[4]={0,0,0,0}, mixb[4]={0,0,0,0};
    for (int s=0;s<32;++s){
      float m = Mrow[s];
      float4 xa = *(const float4*)(xb + s*16384 + off + w0);
      float4 xc = *(const float4*)(xb + s*16384 + off + w0 + 64);
      mixa[0]=fmaf(m,xa.x,mixa[0]); mixa[1]=fmaf(m,xa.y,mixa[1]);
      mixa[2]=fmaf(m,xa.z,mixa[2]); mixa[3]=fmaf(m,xa.w,mixa[3]);
      mixb[0]=fmaf(m,xc.x,mixb[0]); mixb[1]=fmaf(m,xc.y,mixb[1]);
      mixb[2]=fmaf(m,xc.z,mixb[2]); mixb[3]=fmaf(m,xc.w,mixb[3]);
    }
    float oa[4], ob[4];
    #pragma unroll
    for (int j=0;j<4;++j){
      oa[j] = cst + Se[j] + So[j] + mixa[j];
      ob[j] = cst + Se[j] - So[j] + mixb[j];
      s1 += oa[j]+ob[j];
      s2 += oa[j]*oa[j] + ob[j]*ob[j];
      zrows[hl][w0+j]    = oa[j];
      zrows[hl][w0+64+j] = ob[j];
    }
    *(float4*)(z + n*16384 + off + w0)      = make_float4(oa[0],oa[1],oa[2],oa[3]);
    *(float4*)(z + n*16384 + off + w0 + 64) = make_float4(ob[0],ob[1],ob[2],ob[3]);
  }
  __syncthreads();
  // radix-2 over w, then raw row DFT (kw 0..31). tw has dir=+1: negate imag.
  for (int i=threadIdx.x;i<1024;i+=256){
    int hl=i>>6, w=i&63;
    float a=zrows[hl][w], bz=zrows[hl][w+64];
    zrows[hl][w]=a+bz; zrows[hl][w+64]=a-bz;
  }
  __syncthreads();
  for (int i=threadIdx.x;i<512;i+=256){
    int hl=i>>5, kw=i&31;
    int gh = (hl<8)? hb+hl : hb+(hl-8)+64;
    int sel = (kw&1)? 64 : 0;
    float re=0.f, im=0.f; int idx=0;
    for (int w=0;w<64;++w){
      float v=zrows[hl][sel+w]; cf tt=tw[idx];
      re=fmaf(v,tt.x,re); im=fmaf(v,tt.y,im);
      idx=(idx+kw)&127;
    }
    float* d = Tm + ((n*128+gh)*32+kw)*2;
    d[0]=re*(1.f/16384.f); d[1]=-im*(1.f/16384.f);
  }
  breduce2(s1,s2);
  if (threadIdx.x==0){ atomicAdd(&stats[n*2],s1); atomicAdd(&stats[n*2+1],s2); }
}

// fused fwd col DFT + weight + inverse col DFT (radix-2 both); grid (64,4)
// apply_an: load v = C1*T + (kw==0 ? Dc/128 : 0), with C1/Dc from statsZ
__global__ __launch_bounds__(256) void k_colpair(const float* __restrict__ Tm, const float* __restrict__ wM,
                                                 const float* __restrict__ statsZ,
                                                 const float* __restrict__ ng, const float* __restrict__ nb,
                                                 int apply_an, float* __restrict__ Am){
  __shared__ cf Tsh[128][9];
  __shared__ cf Gsh[64][9];
  __shared__ cf tw[128];
  init_tw(tw,128,-1.f);
  int n = blockIdx.x, kw8 = blockIdx.y*8;
  float C1 = 1.f, Dc128 = 0.f;
  if (apply_an){
    float S=statsZ[n*2], S2=statsZ[n*2+1];
    float mz=S*(1.f/16384.f), vz=S2*(1.f/16384.f)-mz*mz;
    float az=rsqrtf(vz+EPSV);
    float g1=ng[1], g2=ng[2];
    float vat = g1*g1*vz*az*az;
    C1 = az*g1*rsqrtf(vat+EPSV)*g2;
    Dc128 = (nb[2] - mz*C1)*(1.f/128.f);
  }
  for (int i=threadIdx.x;i<1024;i+=256){
    int h=i>>3, kwl=i&7;
    cf v = ldc(Tm + ((n*128+h)*32 + kw8+kwl)*2);
    v.x *= C1; v.y *= C1;
    if (apply_an && (kw8+kwl)==0) v.x += Dc128;
    Tsh[h][kwl] = v;
  }
  __syncthreads();
  for (int i=threadIdx.x;i<512;i+=256){
    int h=i>>3, kwl=i&7;
    cf a=Tsh[h][kwl], b=Tsh[h+64][kwl];
    Tsh[h][kwl]    = make_float2(a.x+b.x, a.y+b.y);
    Tsh[h+64][kwl] = make_float2(a.x-b.x, a.y-b.y);
  }
  __syncthreads();
  {
    int kwl = threadIdx.x&7, base = threadIdx.x>>3;
    for (int r=0;r<2;++r){
      int khi = r*32 + base;
      int khF = (khi<32)? khi : khi+64;
      int sel = (khi&1)? 64 : 0;
      float re=0.f, im=0.f; int idx=0;
      for (int j=0;j<64;++j){
        cf v=Tsh[sel+j][kwl]; cf t=tw[idx];
        re += v.x*t.x - v.y*t.y; im += v.x*t.y + v.y*t.x;
        idx=(idx+khF)&127;
      }
      int half=(khi>=32)?1:0, mr=khi&31;
      cf wv = ldc(wM + ((half*32+mr)*32 + kw8+kwl)*2);
      Gsh[khi][kwl] = cmul(make_float2(re,im), wv);
    }
  }
  __syncthreads();
  {
    int kwl = threadIdx.x&7, base = threadIdx.x>>3;
    for (int r=0;r<2;++r){
      int h = r*32 + base;
      float ser=0.f, sei=0.f, sor=0.f, soi=0.f;
      int s2h = (2*h)&127;
      int idx=0;
      for (int khi=0;khi<32;khi+=2){
        cf v=Gsh[khi][kwl]; cf t=tw[idx];
        ser += v.x*t.x + v.y*t.y; sei += v.y*t.x - v.x*t.y;
        idx=(idx+s2h)&127;
      }
      idx=(96*h)&127;
      for (int khi=32;khi<64;khi+=2){
        cf v=Gsh[khi][kwl]; cf t=tw[idx];
        ser += v.x*t.x + v.y*t.y; sei += v.y*t.x - v.x*t.y;
        idx=(idx+s2h)&127;
      }
      idx=h&127;
      for (int khi=1;khi<32;khi+=2){
        cf v=Gsh[khi][kwl]; cf t=tw[idx];
        sor += v.x*t.x + v.y*t.y; soi += v.y*t.x - v.x*t.y;
        idx=(idx+s2h)&127;
      }
      idx=(97*h)&127;
      for (int khi=33;khi<64;khi+=2){
        cf v=Gsh[khi][kwl]; cf t=tw[idx];
        sor += v.x*t.x + v.y*t.y; soi += v.y*t.x - v.x*t.y;
        idx=(idx+s2h)&127;
      }
      stc(Am + ((n*128+h)*32 + kw8+kwl)*2,    make_float2(ser+sor, sei+soi));
      stc(Am + ((n*128+h+64)*32 + kw8+kwl)*2, make_float2(ser-sor, sei-soi));
    }
  }
}

// irfft row (radix-2); writes spatial + stats; optional cross-sum with m0
__global__ __launch_bounds__(256) void k_mirfft_row(const float* __restrict__ Am, float* __restrict__ out,
                                                    float* __restrict__ stats,
                                                    const float* __restrict__ m0, float* __restrict__ statsC,
                                                    int withCross){
  __shared__ cf rowA[16][33];
  __shared__ cf tw[128];
  init_tw(tw,128,1.f);
  int n=blockIdx.x, h0=blockIdx.y*16;
  for (int i=threadIdx.x;i<512;i+=256){
    int hl=i>>5, kw=i&31;
    rowA[hl][kw] = ldc(Am + ((n*128+h0+hl)*32+kw)*2);
  }
  __syncthreads();
  float s=0.f,s2=0.f,s3=0.f;
  for (int i=threadIdx.x;i<1024;i+=256){
    int hl=i>>6, w=i&63;
    int s2w = (2*w)&127;
    float se=0.f, so=0.f;
    int idx=0;
    for (int kwp=0;kwp<16;++kwp){
      cf v=rowA[hl][2*kwp]; cf t=tw[idx];
      float term=v.x*t.x-v.y*t.y;
      se += (kwp? 2.f:1.f)*term;
      idx=(idx+s2w)&127;
    }
    idx = w&127;
    for (int kwp=0;kwp<16;++kwp){
      cf v=rowA[hl][2*kwp+1]; cf t=tw[idx];
      so += 2.f*(v.x*t.x-v.y*t.y);
      idx=(idx+s2w)&127;
    }
    float oa = se+so, ob = se-so;
    int gi = n*16384+(h0+hl)*128+w;
    out[gi]    = oa;
    out[gi+64] = ob;
    s+=oa+ob; s2 += oa*oa + ob*ob;
    if (withCross){
      s3 = fmaf(oa, m0[gi], s3);
      s3 = fmaf(ob, m0[gi+64], s3);
    }
  }
  breduce2(s,s2);
  if (threadIdx.x==0){ atomicAdd(&stats[n*2],s); atomicAdd(&stats[n*2+1],s2); }
  if (withCross){
    float d=0.f;
    breduce2(s3,d);
    if (threadIdx.x==0) atomicAdd(&statsC[n*2],s3);
  }
}

// m0 = gelu(...); writes m0, statsM0, and M1's rfft-row (radix-2)
__global__ __launch_bounds__(256) void k_m0_rfft_row(const float* __restrict__ fno, const float* __restrict__ z,
                              const float* __restrict__ stats0, const float* __restrict__ statsZ,
                              const float* __restrict__ ng, const float* __restrict__ nb,
                              const float* __restrict__ wM0s, const float* __restrict__ bM0s,
                              float* __restrict__ m0out, float* __restrict__ Tm,
                              float* __restrict__ statsM0){
  __shared__ float tile[16][128];
  __shared__ cf tw[128];
  init_tw(tw,128,-1.f);
  int n=blockIdx.x, h0=blockIdx.y*16;
  float S0=stats0[n*2], S02=stats0[n*2+1];
  float m0m=S0*(1.f/16384.f), v0=S02*(1.f/16384.f)-m0m*m0m;
  float A0=rsqrtf(v0+EPSV)*ng[3];
  float B0=nb[3]-m0m*A0;
  float Sz=statsZ[n*2], Sz2=statsZ[n*2+1];
  float mz=Sz*(1.f/16384.f), vz=Sz2*(1.f/16384.f)-mz*mz;
  float az=rsqrtf(vz+EPSV);
  float g1=ng[1], g2=ng[2];
  float vat=g1*g1*vz*az*az;
  float C1=az*g1*rsqrtf(vat+EPSV)*g2;
  float Dc=nb[2]-mz*C1;
  float ws_=wM0s[0], bs_=bM0s[0];
  float sm=0.f, sm2=0.f;
  for (int i=threadIdx.x;i<2048;i+=256){
    int gi = n*16384 + h0*128 + i;
    float nf = fmaf(fno[gi], A0, B0);
    float an = fmaf(z[gi], C1, Dc);
    float pre = nf + fmaf(ws_, an, bs_);
    float gv = 0.5f*pre*(1.f+erff(pre*0.70710678118654752f));
    tile[i>>7][i&127]=gv;
    m0out[gi]=gv;
    sm+=gv; sm2=fmaf(gv,gv,sm2);
  }
  __syncthreads();
  for (int i=threadIdx.x;i<1024;i+=256){
    int hl=i>>6, w=i&63;
    float a=tile[hl][w], b=tile[hl][w+64];
    tile[hl][w]=a+b; tile[hl][w+64]=a-b;
  }
  __syncthreads();
  for (int i=threadIdx.x;i<512;i+=256){
    int hl=i>>5, kw=i&31;
    int sel = (kw&1)? 64:0;
    float re=0.f,im=0.f; int idx=0;
    for (int w=0;w<64;++w){
      float v=tile[hl][sel+w]; cf t=tw[idx];
      re=fmaf(v,t.x,re); im=fmaf(v,t.y,im);
      idx=(idx+kw)&127;
    }
    float* d = Tm + ((n*128+h0+hl)*32+kw)*2;
    d[0]=re*(1.f/16384.f); d[1]=im*(1.f/16384.f);
  }
  breduce2(sm,sm2);
  if (threadIdx.x==0){ atomicAdd(&statsM0[n*2],sm); atomicAdd(&statsM0[n*2+1],sm2); }
}

// out: m1 computed inline (closed-form stats2)
__global__ __launch_bounds__(256) void k_final(const float* __restrict__ f1, const float* __restrict__ m0,
                        const float* __restrict__ z,
                        const float* __restrict__ stats1, const float* __restrict__ statsM0,
                        const float* __restrict__ statsC, const float* __restrict__ statsZ,
                        const float* __restrict__ ng, const float* __restrict__ nb,
                        const float* __restrict__ wM1s, const float* __restrict__ bM1s,
                        float* __restrict__ out){
  int n=blockIdx.x, h0=blockIdx.y*16;
  const float N = 16384.f, iN = 1.f/16384.f;
  float Sf=stats1[n*2], Sf2=stats1[n*2+1];
  float m1m=Sf*iN, v1=Sf2*iN-m1m*m1m;
  float A1=rsqrtf(v1+EPSV)*ng[4];
  float Bc1=nb[4]-m1m*A1;
  float ws_=wM1s[0], K=Bc1+bM1s[0];
  float Sm=statsM0[n*2], Sm2=statsM0[n*2+1], Sfm=statsC[n*2];
  float S1m = A1*Sf + ws_*Sm + N*K;
  float S2m = A1*A1*Sf2 + ws_*ws_*Sm2 + N*K*K + 2.f*A1*ws_*Sfm + 2.f*A1*K*Sf + 2.f*ws_*K*Sm;
  float mean2 = S1m*iN, var2 = S2m*iN - mean2*mean2;
  float A2=rsqrtf(var2+EPSV)*ng[5];
  float B2c=nb[5]-mean2*A2;
  float Sz=statsZ[n*2], Sz2=statsZ[n*2+1];
  float mz=Sz*iN, vz=Sz2*iN-mz*mz;
  float Az=rsqrtf(vz+EPSV)*ng[1];
  float Bz=nb[1]-mz*Az;
  float cf1 = A2*A1, cm0 = A2*ws_, cc = A2*K + B2c;
  for (int i=threadIdx.x;i<2048;i+=256){
    int gi=n*16384+h0*128+i;
    out[gi] = fmaf(f1[gi],cf1, fmaf(m0[gi],cm0, cc)) + fmaf(z[gi],Az,Bz);
  }
}

// ---------------------------------------------------------------------------
extern "C" void kernel_launch(void* const* d_in, const int* in_sizes, int n_in,
                              void* d_out, int out_size, void* d_ws, size_t ws_size,
                              hipStream_t stream){
  (void)in_sizes; (void)n_in; (void)out_size; (void)ws_size;
  const float* x   = (const float*)d_in[0];
  const float* wK  = (const float*)d_in[1];
  const float* wKs = (const float*)d_in[2];
  const float* bKs = (const float*)d_in[3];
  const float* wQ  = (const float*)d_in[4];
  const float* wQs = (const float*)d_in[5];
  const float* bQs = (const float*)d_in[6];
  const float* wV  = (const float*)d_in[7];
  const float* wVs = (const float*)d_in[8];
  const float* bVs = (const float*)d_in[9];
  const float* wP  = (const float*)d_in[10];
  const float* wPs = (const float*)d_in[11];
  const float* bPs = (const float*)d_in[12];
  const float* wM0 = (const float*)d_in[13];
  const float* wM0s= (const float*)d_in[14];
  const float* bM0s= (const float*)d_in[15];
  const float* wM1 = (const float*)d_in[16];
  const float* wM1s= (const float*)d_in[17];
  const float* bM1s= (const float*)d_in[18];
  const float* ng  = (const float*)d_in[19];
  const float* nb  = (const float*)d_in[20];
  float* out = (float*)d_out;
  float* ws  = (float*)d_ws;

  float* F      = ws;                     //   270,336
  float* scoreP = F + 270336;             // 2,097,152
  float* attn   = scoreP + 2097152;       //    65,536
  float* stats  = attn + 65536;           //       640 (zeroed by k_gamma)
  float* Pm     = stats + 640;            //   262,144
  float* gcons  = Pm + 262144;            //       128
  float* gam    = gcons + 128;            //   135,168
  float* normAB = gam + 135168;           //       128
  float* z      = normAB + 128;           // 1,048,576
  float* m0b    = z + 1048576;            // 1,048,576
  float* fx     = m0b + 1048576;          // 1,048,576
  float* Tm     = fx + 1048576;           //   524,288
  float* Am     = Tm + 524288;            //   524,288
  float* statsZ = stats;
  float* stats0 = stats + 128;
  float* stats1 = stats + 256;
  float* statsM0= stats + 384;
  float* statsC = stats + 512;

  k_gamma_xstats<<<96,256,0,stream>>>(wQ,wQs,bQs, wK,wKs,bKs, x, ng, nb, gam, gcons, stats, normAB);
  k_fwd2d<<<64,1024,0,stream>>>(x, normAB, F);
  k_score<<<dim3(32,2,8),256,0,stream>>>(F, gam, scoreP);
  k_softmax<<<dim3(2,32),1024,0,stream>>>(attn, F, gcons, scoreP);
  k_pmode<<<dim3(2,64,4),256,0,stream>>>(F, attn, wV, wVs, wP, wPs, Pm);
  k_zmix<<<dim3(64,8),256,0,stream>>>(x, Pm, attn, normAB, wVs, wPs, wP, bPs, bVs, z, statsZ, Tm);
  k_colpair<<<dim3(64,4),256,0,stream>>>(Tm, wM0, statsZ, ng, nb, 1, Am);
  k_mirfft_row<<<dim3(64,8),256,0,stream>>>(Am, fx, stats0, (const float*)nullptr, (float*)nullptr, 0);
  k_m0_rfft_row<<<dim3(64,8),256,0,stream>>>(fx, z, stats0, statsZ, ng, nb, wM0s, bM0s, m0b, Tm, statsM0);
  k_colpair<<<dim3(64,4),256,0,stream>>>(Tm, wM1, statsZ, ng, nb, 0, Am);
  k_mirfft_row<<<dim3(64,8),256,0,stream>>>(Am, fx, stats1, m0b, statsC, 1);
  k_final<<<dim3(64,8),256,0,stream>>>(fx, m0b, z, stats1, statsM0, statsC, statsZ, ng, nb, wM1s, bM1s, out);
}

// Round 10
// 250.732 us; speedup vs baseline: 1.0818x; 1.0818x over previous
//
#include <hip/hip_runtime.h>
#include <math.h>

// ---------------------------------------------------------------------------
// CODA block on MI355X, fp32. 13 dispatches; all heavy kernels >=256 blocks.
// F on truncated 64x33 grid; scores via Parseval in mode space; A-mix spatial;
// Pm-only inverse transform fused with z assembly + raw row-DFT of z (affine
// applied at colpair load); m1/stats2 via closed-form expansion.
// ---------------------------------------------------------------------------

#define EPSV 1e-5f
#define PI2 6.283185307179586f

typedef float2 cf;

__device__ __forceinline__ cf cmul(cf a, cf b){ return make_float2(a.x*b.x - a.y*b.y, a.x*b.y + a.y*b.x); }
__device__ __forceinline__ cf ldc(const float* p){ return make_float2(p[0], p[1]); }
__device__ __forceinline__ void stc(float* p, cf v){ p[0]=v.x; p[1]=v.y; }

__device__ __forceinline__ void init_tw(cf* tw, int N, float dir){
  for (int j = threadIdx.x; j < N; j += blockDim.x){
    float s, c; sincosf(dir * PI2 * (float)j / (float)N, &s, &c);
    tw[j] = make_float2(c, s);
  }
}

__device__ void breduce2(float& a, float& b){
  __shared__ float sha[16], shb[16];
  for (int off = 32; off > 0; off >>= 1){
    a += __shfl_down(a, off, 64);
    b += __shfl_down(b, off, 64);
  }
  int w = threadIdx.x >> 6, lane = threadIdx.x & 63;
  int nw = (blockDim.x + 63) >> 6;
  if (lane == 0){ sha[w] = a; shb[w] = b; }
  __syncthreads();
  if (threadIdx.x == 0){
    for (int i = 1; i < nw; ++i){ a += sha[i]; b += shb[i]; }
    sha[0] = a; shb[0] = b;
  }
  __syncthreads();
  a = sha[0]; b = shb[0];
  __syncthreads();
}

// ---- spectral attention helpers ------------------------------------------
__device__ __forceinline__ cf kq_mode(const float* w, int o, int kh, int kw){
  if (kw < 16){
    if (kh < 16)  return ldc(w + ((o*16+kh)*16+kw)*2);
    if (kh >= 48) return ldc(w + (((32+o)*16+(kh-48))*16+kw)*2);
  }
  return make_float2(0.f,0.f);
}

// fused: blocks 0..31 = gamma (per head), 32..95 = per-image inorm coeffs
__global__ __launch_bounds__(256) void k_gamma_xstats(
                      const float* __restrict__ wQ, const float* __restrict__ wQs,
                      const float* __restrict__ bQs,
                      const float* __restrict__ wK, const float* __restrict__ wKs,
                      const float* __restrict__ bKs,
                      const float* __restrict__ x, const float* __restrict__ ng,
                      const float* __restrict__ nb,
                      float* __restrict__ gam, float* __restrict__ gcons,
                      float* __restrict__ stats, float* __restrict__ normAB){
  if (blockIdx.x >= 32){
    int n = blockIdx.x - 32;
    const float* im = x + n*16384;
    float s=0.f, s2=0.f;
    for (int i=threadIdx.x;i<16384;i+=256){ float v=im[i]; s+=v; s2=fmaf(v,v,s2); }
    breduce2(s,s2);
    if (threadIdx.x==0){
      float m = s*(1.f/16384.f), var = s2*(1.f/16384.f)-m*m;
      float A = rsqrtf(var+EPSV)*ng[0];
      normAB[n*2]=A; normAB[n*2+1]=nb[0]-m*A;
    }
    return;
  }
  int o = blockIdx.x;
  if (o==0){ for (int i=threadIdx.x;i<640;i+=256) stats[i]=0.f; }
  float sQ=wQs[o], sK=wKs[o];
  for (int m = threadIdx.x; m < 2112; m += 256){
    int kh = m/33, kw = m-kh*33;
    cf g;
    if (kw == 0){
      int mh = (64-kh)&63;
      cf qp = kq_mode(wQ,o,kh,0);  qp.x += sQ;
      cf qm = kq_mode(wQ,o,mh,0);  qm.x += sQ;
      cf qt = make_float2(0.5f*(qp.x+qm.x), 0.5f*(qp.y-qm.y));
      cf kp = kq_mode(wK,o,kh,0);  kp.x += sK;
      cf km = kq_mode(wK,o,mh,0);  km.x += sK;
      cf kt = make_float2(0.5f*(kp.x+km.x), 0.5f*(kp.y-km.y));
      g = make_float2(64.f*(qt.x*kt.x + qt.y*kt.y), 64.f*(qt.y*kt.x - qt.x*kt.y));
    } else if (kw == 32){
      g = make_float2(64.f*sQ*sK, 0.f);
    } else {
      cf q = kq_mode(wQ,o,kh,kw); q.x += sQ;
      cf k = kq_mode(wK,o,kh,kw); k.x += sK;
      g = make_float2(128.f*(q.x*k.x + q.y*k.y), 128.f*(q.y*k.x - q.x*k.y));
    }
    stc(gam + (o*2112+m)*2, g);
  }
  if (threadIdx.x == 0){
    float qt0 = sQ + kq_mode(wQ,o,0,0).x;
    float kt0 = sK + kq_mode(wK,o,0,0).x;
    gcons[o]    = 64.f*bKs[o]*qt0;
    gcons[32+o] = 64.f*bQs[o]*kt0;
    gcons[64+o] = 64.f*bQs[o]*bKs[o];
  }
}

// row rfft of inorm(x), kw 0..32, scaled 1/16384; radix-2 on w; grid (64,8)
__global__ __launch_bounds__(256) void k_rfft_row_x(const float* __restrict__ x, const float* __restrict__ normAB,
                                                    float* __restrict__ Cw){
  __shared__ float tile[16][128];
  __shared__ cf tw[128];
  init_tw(tw, 128, -1.f);
  int n = blockIdx.x, h0 = blockIdx.y*16;
  float A = normAB[n*2], Bc = normAB[n*2+1];
  for (int i=threadIdx.x;i<2048;i+=256) tile[i>>7][i&127] = fmaf(x[n*16384 + h0*128 + i], A, Bc);
  __syncthreads();
  for (int i=threadIdx.x;i<1024;i+=256){
    int hl=i>>6, w=i&63;
    float a=tile[hl][w], b=tile[hl][w+64];
    tile[hl][w]=a+b; tile[hl][w+64]=a-b;
  }
  __syncthreads();
  int hl = threadIdx.x >> 4, kws = threadIdx.x & 15;
  for (int kw=kws; kw<33; kw+=16){
    int sel = (kw&1)? 64 : 0;
    float re=0.f, im=0.f; int idx=0;
    for (int w=0;w<64;++w){
      float v=tile[hl][sel+w]; cf t=tw[idx];
      re=fmaf(v,t.x,re); im=fmaf(v,t.y,im);
      idx=(idx+kw)&127;
    }
    float* d = Cw + (((n*128)+(h0+hl))*33 + kw)*2;
    d[0]=re*(1.f/16384.f); d[1]=im*(1.f/16384.f);
  }
}

// truncated col DFT with radix-2 on h: F[n][r][kw]; grid (64,9)
__global__ __launch_bounds__(256) void k_fcol(const float* __restrict__ Cw, float* __restrict__ F){
  __shared__ cf col[4][128];
  __shared__ cf tw[128];
  init_tw(tw, 128, -1.f);
  int n = blockIdx.x, kwb = blockIdx.y*4;
  for (int i=threadIdx.x;i<512;i+=256){
    int kwl=i>>7, h=i&127; int kw=kwb+kwl;
    col[kwl][h] = (kw<33) ? ldc(Cw + ((n*128+h)*33+kw)*2) : make_float2(0.f,0.f);
  }
  __syncthreads();
  {
    int i = threadIdx.x;
    int kwl = i>>6, h = i&63;
    cf a = col[kwl][h], b = col[kwl][h+64];
    col[kwl][h]    = make_float2(a.x+b.x, a.y+b.y);
    col[kwl][h+64] = make_float2(a.x-b.x, a.y-b.y);
  }
  __syncthreads();
  int r = threadIdx.x & 63, kwl = threadIdx.x >> 6;
  int kw = kwb + kwl;
  if (kw >= 33) return;
  int R = (r<32)? r : r+64;
  int sel = (r&1)? 64 : 0;
  float re=0.f, im=0.f; int idx=0;
  for (int j=0;j<64;++j){
    cf v=col[kwl][sel+j]; cf t=tw[idx];
    re = fmaf(v.x,t.x,re); re = fmaf(-v.y,t.y,re);
    im = fmaf(v.x,t.y,im); im = fmaf(v.y,t.x,im);
    idx=(idx+R)&127;
  }
  stc(F + ((n*64+r)*33+kw)*2, make_float2(re,im));
}

// scoreP partials; grid (32 mk, 2 b, 8 og); 4 heads share one 66-mode E tile
__global__ __launch_bounds__(256) void k_score(const float* __restrict__ F, const float* __restrict__ gam,
                                               float* __restrict__ scoreP){
  __shared__ float2 Esh[66][33];
  __shared__ float2 gsh[4][66];
  int mk = blockIdx.x, b = blockIdx.y, og = blockIdx.z;
  int m0 = mk*66;
  int t = threadIdx.x >> 3, s4 = (threadIdx.x & 7) << 2;
  for (int i = threadIdx.x; i < 2112; i += 256){
    int tt = i/66, j = i - tt*66;
    int m = m0 + j;
    int kh = m/33, kw = m - kh*33;
    const float* Fb = F + (b*32+tt)*4224;
    float2 v;
    if (kw < 32) v = *(const float2*)(Fb + (kh*33+kw)*2);
    else {
      int mh = (64-kh)&63;
      float2 a = *(const float2*)(Fb + (kh*33+32)*2);
      float2 c = *(const float2*)(Fb + (mh*33+32)*2);
      v = make_float2(0.5f*(a.x+c.x), 0.5f*(a.y-c.y));
    }
    Esh[j][tt] = v;
  }
  for (int i = threadIdx.x; i < 264; i += 256){
    int ol = i/66, j = i - ol*66;
    gsh[ol][j] = *(const float2*)(gam + ((og*4+ol)*2112 + m0 + j)*2);
  }
  __syncthreads();
  float acc[4][4];
  #pragma unroll
  for (int a=0;a<4;++a) for (int k=0;k<4;++k) acc[a][k]=0.f;
  #pragma unroll 2
  for (int j=0;j<66;++j){
    float2 et = Esh[j][t];
    float2 e0 = Esh[j][s4+0];
    float2 e1 = Esh[j][s4+1];
    float2 e2 = Esh[j][s4+2];
    float2 e3 = Esh[j][s4+3];
    #pragma unroll
    for (int ol=0;ol<4;++ol){
      float2 g = gsh[ol][j];
      float a  = g.x*et.x - g.y*et.y;
      float bb = g.x*et.y + g.y*et.x;
      acc[ol][0] = fmaf(a,e0.x,fmaf(bb,e0.y,acc[ol][0]));
      acc[ol][1] = fmaf(a,e1.x,fmaf(bb,e1.y,acc[ol][1]));
      acc[ol][2] = fmaf(a,e2.x,fmaf(bb,e2.y,acc[ol][2]));
      acc[ol][3] = fmaf(a,e3.x,fmaf(bb,e3.y,acc[ol][3]));
    }
  }
  #pragma unroll
  for (int ol=0;ol<4;++ol){
    int o = og*4+ol;
    float* sp = scoreP + (((mk*2+b)*32+o)*32 + t)*32 + s4;
    sp[0]=acc[ol][0]; sp[1]=acc[ol][1]; sp[2]=acc[ol][2]; sp[3]=acc[ol][3];
  }
}

// sum 32 partials + DC-linear terms, softmax over s -> attn
__global__ __launch_bounds__(1024) void k_softmax(float* __restrict__ attn, const float* __restrict__ F,
                                                const float* __restrict__ gcons, const float* __restrict__ scoreP){
  __shared__ float Ssh[32][33];
  int b = blockIdx.x, o = blockIdx.y;
  int t = threadIdx.x >> 5, s = threadIdx.x & 31;
  float c0=gcons[o], c1=gcons[32+o], c2=gcons[64+o];
  float sc = c0*F[(b*32+t)*4224] + c1*F[(b*32+s)*4224] + c2;
  #pragma unroll 8
  for (int p=0;p<32;++p) sc += scoreP[(((p*2+b)*32+o)*32 + t)*32 + s];
  Ssh[t][s] = sc;
  __syncthreads();
  float mx = -1e30f;
  for (int ss=0;ss<32;++ss) mx = fmaxf(mx, Ssh[t][ss]);
  float e = expf(sc - mx);
  __syncthreads();
  Ssh[t][s] = e;
  __syncthreads();
  float sum = 0.f;
  for (int ss=0;ss<32;++ss) sum += Ssh[t][ss];
  attn[(b*32+o)*1024 + t*32 + s] = e/sum;
}

__device__ __forceinline__ cf wcV_col0(const float* wV, int o, int fr){
  if (fr < 16)  return ldc(wV + ((o*16+fr)*16)*2);
  if (fr >= 112) return ldc(wV + (((32+o)*16+(fr-112))*16)*2);
  return make_float2(0.f,0.f);
}

// Pm[b,t,mh,kw] = sum_o d[o,m] * sum_s attn[b,o,t,s]*F[bs,m]; grid (2,64,4)
__global__ __launch_bounds__(256) void k_pmode(const float* __restrict__ F, const float* __restrict__ attn,
                        const float* __restrict__ wV, const float* __restrict__ wVs,
                        const float* __restrict__ wP, const float* __restrict__ wPs,
                        float* __restrict__ Pm){
  __shared__ float att[32][8][32];
  __shared__ cf Fsh[32][32];
  __shared__ cf dsh[32][32];
  int b = blockIdx.x, mh = blockIdx.y, tg = blockIdx.z;
  int fr = mh<32 ? mh : mh+64;
  int half = (mh>=32)?1:0, mr = mh&31;
  for (int i=threadIdx.x; i<8192; i+=256){
    int o = i>>8, r = i&255;
    att[o][r>>5][r&31] = attn[(b*32+o)*1024 + tg*256 + r];
  }
  for (int i=threadIdx.x; i<1024; i+=256){
    int s=i>>5, kw=i&31;
    Fsh[s][kw] = ldc(F + (((b*32+s)*64+mh)*33+kw)*2);
  }
  for (int i=threadIdx.x; i<1024; i+=256){
    int o=i>>5, kw=i&31;
    cf wp = ldc(wP + (((half*32+o)*32+mr)*32+kw)*2);
    cf bP = make_float2(wPs[o]+wp.x, wp.y);
    cf aV = make_float2(wVs[o], 0.f);
    if (kw==0){
      cf w1 = wcV_col0(wV,o,fr);
      cf w2 = wcV_col0(wV,o,(128-fr)&127);
      aV.x += 0.5f*(w1.x + w2.x);
      aV.y += 0.5f*(w1.y - w2.y);
    } else if (kw<16){
      if (fr<16){ cf wv=ldc(wV + ((o*16+fr)*16+kw)*2); aV.x+=wv.x; aV.y+=wv.y; }
      else if (fr>=112){ cf wv=ldc(wV + (((32+o)*16+(fr-112))*16+kw)*2); aV.x+=wv.x; aV.y+=wv.y; }
    }
    cf c = cmul(bP, aV);
    c.x -= wPs[o]*wVs[o];
    dsh[o][kw]=c;
  }
  __syncthreads();
  int tl = threadIdx.x>>5, kw = threadIdx.x&31;
  float ax=0.f, ay=0.f;
  for (int o=0;o<32;++o){
    float er=0.f, ei=0.f;
    #pragma unroll
    for (int s4=0;s4<32;s4+=4){
      float4 a4 = *(const float4*)&att[o][tl][s4];
      cf f0=Fsh[s4][kw], f1=Fsh[s4+1][kw], f2=Fsh[s4+2][kw], f3=Fsh[s4+3][kw];
      er=fmaf(a4.x,f0.x,er); ei=fmaf(a4.x,f0.y,ei);
      er=fmaf(a4.y,f1.x,er); ei=fmaf(a4.y,f1.y,ei);
      er=fmaf(a4.z,f2.x,er); ei=fmaf(a4.z,f2.y,ei);
      er=fmaf(a4.w,f3.x,er); ei=fmaf(a4.w,f3.y,ei);
    }
    cf d = dsh[o][kw];
    ax += d.x*er - d.y*ei;
    ay += d.x*ei + d.y*er;
  }
  int t = tg*8+tl;
  stc(Pm + ((b*32+t)*2048 + mh*32+kw)*2, make_float2(ax,ay));
}

// z = spatial A-mix of x + irfft2(Pm) + consts; stats; ALSO raw row-DFT of z
// -> Tm (kw 0..31, scale 1/16384, no an-affine). grid (64, 8 hb)
__global__ __launch_bounds__(256) void k_zmix(const float* __restrict__ x, const float* __restrict__ Pm,
                        const float* __restrict__ attn, const float* __restrict__ normAB,
                        const float* __restrict__ wVs, const float* __restrict__ wPs,
                        const float* __restrict__ wP, const float* __restrict__ bPs,
                        const float* __restrict__ bVs,
                        float* __restrict__ z, float* __restrict__ stats,
                        float* __restrict__ Tm){
  __shared__ cf Pmsh[64][33];
  __shared__ cf PmAsh[16][33];
  __shared__ float zrows[16][128];
  __shared__ float Mrow[32];
  __shared__ float cpart[33];
  __shared__ float consts;
  __shared__ cf tw[128];
  init_tw(tw, 128, 1.f);
  int n = blockIdx.x, b = n>>5, t = n&31, hb = blockIdx.y*8;
  for (int i=threadIdx.x;i<2048;i+=256)
    Pmsh[i>>5][i&31] = ldc(Pm + (n*2048 + i)*2);
  if (threadIdx.x < 32){
    int s = threadIdx.x;
    float a=0.f;
    for (int o=0;o<32;++o) a = fmaf(attn[(b*32+o)*1024 + t*32 + s], wVs[o]*wPs[o], a);
    float AxS = normAB[(b*32+s)*2], BcS = normAB[(b*32+s)*2+1];
    Mrow[s] = fmaf(a, AxS, (s==t)?1.f:0.f);
    cpart[s] = a*BcS;
  } else if (threadIdx.x == 32){
    float dcx = bPs[0];
    for (int o=0;o<32;++o){
      cf wp = ldc(wP + (o*1024)*2);
      dcx += (wPs[o]+wp.x)*bVs[o];
    }
    cpart[32] = dcx;
  }
  __syncthreads();
  if (threadIdx.x == 0){
    float c=0.f;
    for (int i=0;i<33;++i) c += cpart[i];
    consts = c;
  }
  {
    int bl = threadIdx.x>>5, kw = threadIdx.x&31;
    int h = hb + bl;
    float ser=0.f, sei=0.f, sor=0.f, soi=0.f;
    int s2h = (2*h)&127;
    int idx = 0;
    for (int khi=0;khi<32;khi+=2){
      cf v=Pmsh[khi][kw]; cf tt=tw[idx];
      ser += v.x*tt.x - v.y*tt.y; sei += v.x*tt.y + v.y*tt.x;
      idx=(idx+s2h)&127;
    }
    idx = (96*h)&127;
    for (int khi=32;khi<64;khi+=2){
      cf v=Pmsh[khi][kw]; cf tt=tw[idx];
      ser += v.x*tt.x - v.y*tt.y; sei += v.x*tt.y + v.y*tt.x;
      idx=(idx+s2h)&127;
    }
    idx = h&127;
    for (int khi=1;khi<32;khi+=2){
      cf v=Pmsh[khi][kw]; cf tt=tw[idx];
      sor += v.x*tt.x - v.y*tt.y; soi += v.x*tt.y + v.y*tt.x;
      idx=(idx+s2h)&127;
    }
    idx = (97*h)&127;
    for (int khi=33;khi<64;khi+=2){
      cf v=Pmsh[khi][kw]; cf tt=tw[idx];
      sor += v.x*tt.x - v.y*tt.y; soi += v.x*tt.y + v.y*tt.x;
      idx=(idx+s2h)&127;
    }
    PmAsh[bl][kw]   = make_float2(ser+sor, sei+soi);
    PmAsh[8+bl][kw] = make_float2(ser-sor, sei-soi);
  }
  __syncthreads();
  float cst = consts;
  float s1=0.f, s2=0.f;
  const float* xb = x + b*32*16384;
  {
    int hl = threadIdx.x>>4, wg = threadIdx.x&15;
    int w0 = wg*4;
    int gh = (hl<8)? hb+hl : hb+(hl-8)+64;
    int off = gh*128;
    float Se[4], So[4];
    #pragma unroll
    for (int j=0;j<4;++j){
      int w = w0+j;
      int s2w = (2*w)&127;
      float se=0.f, so=0.f;
      int idx=0;
      for (int kwp=0;kwp<16;++kwp){
        cf v = PmAsh[hl][2*kwp]; cf tt=tw[idx];
        float term = v.x*tt.x - v.y*tt.y;
        se += (kwp? 2.f:1.f)*term;
        idx=(idx+s2w)&127;
      }
      idx = w&127;
      for (int kwp=0;kwp<16;++kwp){
        cf v = PmAsh[hl][2*kwp+1]; cf tt=tw[idx];
        so += 2.f*(v.x*tt.x - v.y*tt.y);
        idx=(idx+s2w)&127;
      }
      Se[j]=se; So[j]=so;
    }
    float mixa[4]={0,0,0,0}, mixb[4]={0,0,0,0};
    for (int s=0;s<32;++s){
      float m = Mrow[s];
      float4 xa = *(const float4*)(xb + s*16384 + off + w0);
      float4 xc = *(const float4*)(xb + s*16384 + off + w0 + 64);
      mixa[0]=fmaf(m,xa.x,mixa[0]); mixa[1]=fmaf(m,xa.y,mixa[1]);
      mixa[2]=fmaf(m,xa.z,mixa[2]); mixa[3]=fmaf(m,xa.w,mixa[3]);
      mixb[0]=fmaf(m,xc.x,mixb[0]); mixb[1]=fmaf(m,xc.y,mixb[1]);
      mixb[2]=fmaf(m,xc.z,mixb[2]); mixb[3]=fmaf(m,xc.w,mixb[3]);
    }
    float oa[4], ob[4];
    #pragma unroll
    for (int j=0;j<4;++j){
      oa[j] = cst + Se[j] + So[j] + mixa[j];
      ob[j] = cst + Se[j] - So[j] + mixb[j];
      s1 += oa[j]+ob[j];
      s2 += oa[j]*oa[j] + ob[j]*ob[j];
      zrows[hl][w0+j]    = oa[j];
      zrows[hl][w0+64+j] = ob[j];
    }
    *(float4*)(z + n*16384 + off + w0)      = make_float4(oa[0],oa[1],oa[2],oa[3]);
    *(float4*)(z + n*16384 + off + w0 + 64) = make_float4(ob[0],ob[1],ob[2],ob[3]);
  }
  __syncthreads();
  for (int i=threadIdx.x;i<1024;i+=256){
    int hl=i>>6, w=i&63;
    float a=zrows[hl][w], bz=zrows[hl][w+64];
    zrows[hl][w]=a+bz; zrows[hl][w+64]=a-bz;
  }
  __syncthreads();
  for (int i=threadIdx.x;i<512;i+=256){
    int hl=i>>5, kw=i&31;
    int gh = (hl<8)? hb+hl : hb+(hl-8)+64;
    int sel = (kw&1)? 64 : 0;
    float re=0.f, im=0.f; int idx=0;
    for (int w=0;w<64;++w){
      float v=zrows[hl][sel+w]; cf tt=tw[idx];
      re=fmaf(v,tt.x,re); im=fmaf(v,tt.y,im);
      idx=(idx+kw)&127;
    }
    float* d = Tm + ((n*128+gh)*32+kw)*2;
    d[0]=re*(1.f/16384.f); d[1]=-im*(1.f/16384.f);
  }
  breduce2(s1,s2);
  if (threadIdx.x==0){ atomicAdd(&stats[n*2],s1); atomicAdd(&stats[n*2+1],s2); }
}

// fused fwd col DFT + weight + inverse col DFT (radix-2 both); grid (64,4)
// apply_an: load v = C1*T + (kw==0 ? Dc/128 : 0), with C1/Dc from statsZ
__global__ __launch_bounds__(256) void k_colpair(const float* __restrict__ Tm, const float* __restrict__ wM,
                                                 const float* __restrict__ statsZ,
                                                 const float* __restrict__ ng, const float* __restrict__ nb,
                                                 int apply_an, float* __restrict__ Am){
  __shared__ cf Tsh[128][9];
  __shared__ cf Gsh[64][9];
  __shared__ cf tw[128];
  init_tw(tw,128,-1.f);
  int n = blockIdx.x, kw8 = blockIdx.y*8;
  float C1 = 1.f, Dc128 = 0.f;
  if (apply_an){
    float S=statsZ[n*2], S2=statsZ[n*2+1];
    float mz=S*(1.f/16384.f), vz=S2*(1.f/16384.f)-mz*mz;
    float az=rsqrtf(vz+EPSV);
    float g1=ng[1], g2=ng[2];
    float vat = g1*g1*vz*az*az;
    C1 = az*g1*rsqrtf(vat+EPSV)*g2;
    Dc128 = (nb[2] - mz*C1)*(1.f/128.f);
  }
  for (int i=threadIdx.x;i<1024;i+=256){
    int h=i>>3, kwl=i&7;
    cf v = ldc(Tm + ((n*128+h)*32 + kw8+kwl)*2);
    v.x *= C1; v.y *= C1;
    if (apply_an && (kw8+kwl)==0) v.x += Dc128;
    Tsh[h][kwl] = v;
  }
  __syncthreads();
  for (int i=threadIdx.x;i<512;i+=256){
    int h=i>>3, kwl=i&7;
    cf a=Tsh[h][kwl], b=Tsh[h+64][kwl];
    Tsh[h][kwl]    = make_float2(a.x+b.x, a.y+b.y);
    Tsh[h+64][kwl] = make_float2(a.x-b.x, a.y-b.y);
  }
  __syncthreads();
  {
    int kwl = threadIdx.x&7, base = threadIdx.x>>3;
    for (int r=0;r<2;++r){
      int khi = r*32 + base;
      int khF = (khi<32)? khi : khi+64;
      int sel = (khi&1)? 64 : 0;
      float re=0.f, im=0.f; int idx=0;
      for (int j=0;j<64;++j){
        cf v=Tsh[sel+j][kwl]; cf t=tw[idx];
        re += v.x*t.x - v.y*t.y; im += v.x*t.y + v.y*t.x;
        idx=(idx+khF)&127;
      }
      int half=(khi>=32)?1:0, mr=khi&31;
      cf wv = ldc(wM + ((half*32+mr)*32 + kw8+kwl)*2);
      Gsh[khi][kwl] = cmul(make_float2(re,im), wv);
    }
  }
  __syncthreads();
  {
    int kwl = threadIdx.x&7, base = threadIdx.x>>3;
    for (int r=0;r<2;++r){
      int h = r*32 + base;
      float ser=0.f, sei=0.f, sor=0.f, soi=0.f;
      int s2h = (2*h)&127;
      int idx=0;
      for (int khi=0;khi<32;khi+=2){
        cf v=Gsh[khi][kwl]; cf t=tw[idx];
        ser += v.x*t.x + v.y*t.y; sei += v.y*t.x - v.x*t.y;
        idx=(idx+s2h)&127;
      }
      idx=(96*h)&127;
      for (int khi=32;khi<64;khi+=2){
        cf v=Gsh[khi][kwl]; cf t=tw[idx];
        ser += v.x*t.x + v.y*t.y; sei += v.y*t.x - v.x*t.y;
        idx=(idx+s2h)&127;
      }
      idx=h&127;
      for (int khi=1;khi<32;khi+=2){
        cf v=Gsh[khi][kwl]; cf t=tw[idx];
        sor += v.x*t.x + v.y*t.y; soi += v.y*t.x - v.x*t.y;
        idx=(idx+s2h)&127;
      }
      idx=(97*h)&127;
      for (int khi=33;khi<64;khi+=2){
        cf v=Gsh[khi][kwl]; cf t=tw[idx];
        sor += v.x*t.x + v.y*t.y; soi += v.y*t.x - v.x*t.y;
        idx=(idx+s2h)&127;
      }
      stc(Am + ((n*128+h)*32 + kw8+kwl)*2,    make_float2(ser+sor, sei+soi));
      stc(Am + ((n*128+h+64)*32 + kw8+kwl)*2, make_float2(ser-sor, sei-soi));
    }
  }
}

// irfft row (radix-2); writes spatial + stats; optional cross-sum with m0
__global__ __launch_bounds__(256) void k_mirfft_row(const float* __restrict__ Am, float* __restrict__ out,
                                                    float* __restrict__ stats,
                                                    const float* __restrict__ m0, float* __restrict__ statsC,
                                                    int withCross){
  __shared__ cf rowA[16][33];
  __shared__ cf tw[128];
  init_tw(tw,128,1.f);
  int n=blockIdx.x, h0=blockIdx.y*16;
  for (int i=threadIdx.x;i<512;i+=256){
    int hl=i>>5, kw=i&31;
    rowA[hl][kw] = ldc(Am + ((n*128+h0+hl)*32+kw)*2);
  }
  __syncthreads();
  float s=0.f,s2=0.f,s3=0.f;
  for (int i=threadIdx.x;i<1024;i+=256){
    int hl=i>>6, w=i&63;
    int s2w = (2*w)&127;
    float se=0.f, so=0.f;
    int idx=0;
    for (int kwp=0;kwp<16;++kwp){
      cf v=rowA[hl][2*kwp]; cf t=tw[idx];
      float term=v.x*t.x-v.y*t.y;
      se += (kwp? 2.f:1.f)*term;
      idx=(idx+s2w)&127;
    }
    idx = w&127;
    for (int kwp=0;kwp<16;++kwp){
      cf v=rowA[hl][2*kwp+1]; cf t=tw[idx];
      so += 2.f*(v.x*t.x-v.y*t.y);
      idx=(idx+s2w)&127;
    }
    float oa = se+so, ob = se-so;
    int gi = n*16384+(h0+hl)*128+w;
    out[gi]    = oa;
    out[gi+64] = ob;
    s+=oa+ob; s2 += oa*oa + ob*ob;
    if (withCross){
      s3 = fmaf(oa, m0[gi], s3);
      s3 = fmaf(ob, m0[gi+64], s3);
    }
  }
  breduce2(s,s2);
  if (threadIdx.x==0){ atomicAdd(&stats[n*2],s); atomicAdd(&stats[n*2+1],s2); }
  if (withCross){
    float d=0.f;
    breduce2(s3,d);
    if (threadIdx.x==0) atomicAdd(&statsC[n*2],s3);
  }
}

// m0 = gelu(...); writes m0, statsM0, and M1's rfft-row (radix-2)
__global__ __launch_bounds__(256) void k_m0_rfft_row(const float* __restrict__ fno, const float* __restrict__ z,
                              const float* __restrict__ stats0, const float* __restrict__ statsZ,
                              const float* __restrict__ ng, const float* __restrict__ nb,
                              const float* __restrict__ wM0s, const float* __restrict__ bM0s,
                              float* __restrict__ m0out, float* __restrict__ Tm,
                              float* __restrict__ statsM0){
  __shared__ float tile[16][128];
  __shared__ cf tw[128];
  init_tw(tw,128,-1.f);
  int n=blockIdx.x, h0=blockIdx.y*16;
  float S0=stats0[n*2], S02=stats0[n*2+1];
  float m0m=S0*(1.f/16384.f), v0=S02*(1.f/16384.f)-m0m*m0m;
  float A0=rsqrtf(v0+EPSV)*ng[3];
  float B0=nb[3]-m0m*A0;
  float Sz=statsZ[n*2], Sz2=statsZ[n*2+1];
  float mz=Sz*(1.f/16384.f), vz=Sz2*(1.f/16384.f)-mz*mz;
  float az=rsqrtf(vz+EPSV);
  float g1=ng[1], g2=ng[2];
  float vat=g1*g1*vz*az*az;
  float C1=az*g1*rsqrtf(vat+EPSV)*g2;
  float Dc=nb[2]-mz*C1;
  float ws_=wM0s[0], bs_=bM0s[0];
  float sm=0.f, sm2=0.f;
  for (int i=threadIdx.x;i<2048;i+=256){
    int gi = n*16384 + h0*128 + i;
    float nf = fmaf(fno[gi], A0, B0);
    float an = fmaf(z[gi], C1, Dc);
    float pre = nf + fmaf(ws_, an, bs_);
    float gv = 0.5f*pre*(1.f+erff(pre*0.70710678118654752f));
    tile[i>>7][i&127]=gv;
    m0out[gi]=gv;
    sm+=gv; sm2=fmaf(gv,gv,sm2);
  }
  __syncthreads();
  for (int i=threadIdx.x;i<1024;i+=256){
    int hl=i>>6, w=i&63;
    float a=tile[hl][w], b=tile[hl][w+64];
    tile[hl][w]=a+b; tile[hl][w+64]=a-b;
  }
  __syncthreads();
  for (int i=threadIdx.x;i<512;i+=256){
    int hl=i>>5, kw=i&31;
    int sel = (kw&1)? 64:0;
    float re=0.f,im=0.f; int idx=0;
    for (int w=0;w<64;++w){
      float v=tile[hl][sel+w]; cf t=tw[idx];
      re=fmaf(v,t.x,re); im=fmaf(v,t.y,im);
      idx=(idx+kw)&127;
    }
    float* d = Tm + ((n*128+h0+hl)*32+kw)*2;
    d[0]=re*(1.f/16384.f); d[1]=im*(1.f/16384.f);
  }
  breduce2(sm,sm2);
  if (threadIdx.x==0){ atomicAdd(&statsM0[n*2],sm); atomicAdd(&statsM0[n*2+1],sm2); }
}

// out: m1 computed inline (closed-form stats2)
__global__ __launch_bounds__(256) void k_final(const float* __restrict__ f1, const float* __restrict__ m0,
                        const float* __restrict__ z,
                        const float* __restrict__ stats1, const float* __restrict__ statsM0,
                        const float* __restrict__ statsC, const float* __restrict__ statsZ,
                        const float* __restrict__ ng, const float* __restrict__ nb,
                        const float* __restrict__ wM1s, const float* __restrict__ bM1s,
                        float* __restrict__ out){
  int n=blockIdx.x, h0=blockIdx.y*16;
  const float N = 16384.f, iN = 1.f/16384.f;
  float Sf=stats1[n*2], Sf2=stats1[n*2+1];
  float m1m=Sf*iN, v1=Sf2*iN-m1m*m1m;
  float A1=rsqrtf(v1+EPSV)*ng[4];
  float Bc1=nb[4]-m1m*A1;
  float ws_=wM1s[0], K=Bc1+bM1s[0];
  float Sm=statsM0[n*2], Sm2=statsM0[n*2+1], Sfm=statsC[n*2];
  float S1m = A1*Sf + ws_*Sm + N*K;
  float S2m = A1*A1*Sf2 + ws_*ws_*Sm2 + N*K*K + 2.f*A1*ws_*Sfm + 2.f*A1*K*Sf + 2.f*ws_*K*Sm;
  float mean2 = S1m*iN, var2 = S2m*iN - mean2*mean2;
  float A2=rsqrtf(var2+EPSV)*ng[5];
  float B2c=nb[5]-mean2*A2;
  float Sz=statsZ[n*2], Sz2=statsZ[n*2+1];
  float mz=Sz*iN, vz=Sz2*iN-mz*mz;
  float Az=rsqrtf(vz+EPSV)*ng[1];
  float Bz=nb[1]-mz*Az;
  float cf1 = A2*A1, cm0 = A2*ws_, cc = A2*K + B2c;
  for (int i=threadIdx.x;i<2048;i+=256){
    int gi=n*16384+h0*128+i;
    out[gi] = fmaf(f1[gi],cf1, fmaf(m0[gi],cm0, cc)) + fmaf(z[gi],Az,Bz);
  }
}

// ---------------------------------------------------------------------------
extern "C" void kernel_launch(void* const* d_in, const int* in_sizes, int n_in,
                              void* d_out, int out_size, void* d_ws, size_t ws_size,
                              hipStream_t stream){
  (void)in_sizes; (void)n_in; (void)out_size; (void)ws_size;
  const float* x   = (const float*)d_in[0];
  const float* wK  = (const float*)d_in[1];
  const float* wKs = (const float*)d_in[2];
  const float* bKs = (const float*)d_in[3];
  const float* wQ  = (const float*)d_in[4];
  const float* wQs = (const float*)d_in[5];
  const float* bQs = (const float*)d_in[6];
  const float* wV  = (const float*)d_in[7];
  const float* wVs = (const float*)d_in[8];
  const float* bVs = (const float*)d_in[9];
  const float* wP  = (const float*)d_in[10];
  const float* wPs = (const float*)d_in[11];
  const float* bPs = (const float*)d_in[12];
  const float* wM0 = (const float*)d_in[13];
  const float* wM0s= (const float*)d_in[14];
  const float* bM0s= (const float*)d_in[15];
  const float* wM1 = (const float*)d_in[16];
  const float* wM1s= (const float*)d_in[17];
  const float* bM1s= (const float*)d_in[18];
  const float* ng  = (const float*)d_in[19];
  const float* nb  = (const float*)d_in[20];
  float* out = (float*)d_out;
  float* ws  = (float*)d_ws;

  float* F      = ws;                     //   270,336
  float* Cw     = F + 270336;             //   540,672
  float* scoreP = Cw + 540672;            // 2,097,152
  float* attn   = scoreP + 2097152;       //    65,536
  float* stats  = attn + 65536;           //       640 (zeroed by k_gamma)
  float* Pm     = stats + 640;            //   262,144
  float* gcons  = Pm + 262144;            //       128
  float* gam    = gcons + 128;            //   135,168
  float* normAB = gam + 135168;           //       128
  float* z      = normAB + 128;           // 1,048,576
  float* m0b    = z + 1048576;            // 1,048,576
  float* fx     = m0b + 1048576;          // 1,048,576
  float* Tm     = fx + 1048576;           //   524,288
  float* Am     = Tm + 524288;            //   524,288
  float* statsZ = stats;
  float* stats0 = stats + 128;
  float* stats1 = stats + 256;
  float* statsM0= stats + 384;
  float* statsC = stats + 512;

  k_gamma_xstats<<<96,256,0,stream>>>(wQ,wQs,bQs, wK,wKs,bKs, x, ng, nb, gam, gcons, stats, normAB);
  k_rfft_row_x<<<dim3(64,8),256,0,stream>>>(x, normAB, Cw);
  k_fcol<<<dim3(64,9),256,0,stream>>>(Cw, F);
  k_score<<<dim3(32,2,8),256,0,stream>>>(F, gam, scoreP);
  k_softmax<<<dim3(2,32),1024,0,stream>>>(attn, F, gcons, scoreP);
  k_pmode<<<dim3(2,64,4),256,0,stream>>>(F, attn, wV, wVs, wP, wPs, Pm);
  k_zmix<<<dim3(64,8),256,0,stream>>>(x, Pm, attn, normAB, wVs, wPs, wP, bPs, bVs, z, statsZ, Tm);
  k_colpair<<<dim3(64,4),256,0,stream>>>(Tm, wM0, statsZ, ng, nb, 1, Am);
  k_mirfft_row<<<dim3(64,8),256,0,stream>>>(Am, fx, stats0, (const float*)nullptr, (float*)nullptr, 0);
  k_m0_rfft_row<<<dim3(64,8),256,0,stream>>>(fx, z, stats0, statsZ, ng, nb, wM0s, bM0s, m0b, Tm, statsM0);
  k_colpair<<<dim3(64,4),256,0,stream>>>(Tm, wM1, statsZ, ng, nb, 0, Am);
  k_mirfft_row<<<dim3(64,8),256,0,stream>>>(Am, fx, stats1, m0b, statsC, 1);
  k_final<<<dim3(64,8),256,0,stream>>>(fx, m0b, z, stats1, statsM0, statsC, statsZ, ng, nb, wM1s, bM1s, out);
}

// Round 11
// 234.129 us; speedup vs baseline: 1.1585x; 1.0709x over previous
//
#include <hip/hip_runtime.h>
#include <math.h>

// ---------------------------------------------------------------------------
// CODA block on MI355X, fp32. 11 dispatches; all heavy kernels >=256 blocks.
// F on truncated 64x33 grid; scores via Parseval in mode space; A-mix spatial;
// Pm-only inverse transform fused with z assembly + raw row-DFT of z; FNO
// layer stats (mean/var of f0,f1 and cross f1*m0) computed IN MODE SPACE via
// Parseval inside k_colpair, letting the irfft-row stages fuse into their
// consumers (k_m0_irow, k_final_irow).
// ---------------------------------------------------------------------------

#define EPSV 1e-5f
#define PI2 6.283185307179586f

typedef float2 cf;

__device__ __forceinline__ cf cmul(cf a, cf b){ return make_float2(a.x*b.x - a.y*b.y, a.x*b.y + a.y*b.x); }
__device__ __forceinline__ cf ldc(const float* p){ return make_float2(p[0], p[1]); }
__device__ __forceinline__ void stc(float* p, cf v){ p[0]=v.x; p[1]=v.y; }

__device__ __forceinline__ void init_tw(cf* tw, int N, float dir){
  for (int j = threadIdx.x; j < N; j += blockDim.x){
    float s, c; sincosf(dir * PI2 * (float)j / (float)N, &s, &c);
    tw[j] = make_float2(c, s);
  }
}

__device__ void breduce2(float& a, float& b){
  __shared__ float sha[16], shb[16];
  for (int off = 32; off > 0; off >>= 1){
    a += __shfl_down(a, off, 64);
    b += __shfl_down(b, off, 64);
  }
  int w = threadIdx.x >> 6, lane = threadIdx.x & 63;
  int nw = (blockDim.x + 63) >> 6;
  if (lane == 0){ sha[w] = a; shb[w] = b; }
  __syncthreads();
  if (threadIdx.x == 0){
    for (int i = 1; i < nw; ++i){ a += sha[i]; b += shb[i]; }
    sha[0] = a; shb[0] = b;
  }
  __syncthreads();
  a = sha[0]; b = shb[0];
  __syncthreads();
}

// ---- spectral attention helpers ------------------------------------------
__device__ __forceinline__ cf kq_mode(const float* w, int o, int kh, int kw){
  if (kw < 16){
    if (kh < 16)  return ldc(w + ((o*16+kh)*16+kw)*2);
    if (kh >= 48) return ldc(w + (((32+o)*16+(kh-48))*16+kw)*2);
  }
  return make_float2(0.f,0.f);
}

// fused: blocks 0..31 = gamma (per head), 32..95 = per-image inorm coeffs
__global__ __launch_bounds__(256) void k_gamma_xstats(
                      const float* __restrict__ wQ, const float* __restrict__ wQs,
                      const float* __restrict__ bQs,
                      const float* __restrict__ wK, const float* __restrict__ wKs,
                      const float* __restrict__ bKs,
                      const float* __restrict__ x, const float* __restrict__ ng,
                      const float* __restrict__ nb,
                      float* __restrict__ gam, float* __restrict__ gcons,
                      float* __restrict__ stats, float* __restrict__ normAB){
  if (blockIdx.x >= 32){
    int n = blockIdx.x - 32;
    const float* im = x + n*16384;
    float s=0.f, s2=0.f;
    for (int i=threadIdx.x;i<16384;i+=256){ float v=im[i]; s+=v; s2=fmaf(v,v,s2); }
    breduce2(s,s2);
    if (threadIdx.x==0){
      float m = s*(1.f/16384.f), var = s2*(1.f/16384.f)-m*m;
      float A = rsqrtf(var+EPSV)*ng[0];
      normAB[n*2]=A; normAB[n*2+1]=nb[0]-m*A;
    }
    return;
  }
  int o = blockIdx.x;
  if (o==0){ for (int i=threadIdx.x;i<640;i+=256) stats[i]=0.f; }
  float sQ=wQs[o], sK=wKs[o];
  for (int m = threadIdx.x; m < 2112; m += 256){
    int kh = m/33, kw = m-kh*33;
    cf g;
    if (kw == 0){
      int mh = (64-kh)&63;
      cf qp = kq_mode(wQ,o,kh,0);  qp.x += sQ;
      cf qm = kq_mode(wQ,o,mh,0);  qm.x += sQ;
      cf qt = make_float2(0.5f*(qp.x+qm.x), 0.5f*(qp.y-qm.y));
      cf kp = kq_mode(wK,o,kh,0);  kp.x += sK;
      cf km = kq_mode(wK,o,mh,0);  km.x += sK;
      cf kt = make_float2(0.5f*(kp.x+km.x), 0.5f*(kp.y-km.y));
      g = make_float2(64.f*(qt.x*kt.x + qt.y*kt.y), 64.f*(qt.y*kt.x - qt.x*kt.y));
    } else if (kw == 32){
      g = make_float2(64.f*sQ*sK, 0.f);
    } else {
      cf q = kq_mode(wQ,o,kh,kw); q.x += sQ;
      cf k = kq_mode(wK,o,kh,kw); k.x += sK;
      g = make_float2(128.f*(q.x*k.x + q.y*k.y), 128.f*(q.y*k.x - q.x*k.y));
    }
    stc(gam + (o*2112+m)*2, g);
  }
  if (threadIdx.x == 0){
    float qt0 = sQ + kq_mode(wQ,o,0,0).x;
    float kt0 = sK + kq_mode(wK,o,0,0).x;
    gcons[o]    = 64.f*bKs[o]*qt0;
    gcons[32+o] = 64.f*bQs[o]*kt0;
    gcons[64+o] = 64.f*bQs[o]*bKs[o];
  }
}

// row rfft of inorm(x), kw 0..32, scaled 1/16384; radix-2 on w; grid (64,8)
__global__ __launch_bounds__(256) void k_rfft_row_x(const float* __restrict__ x, const float* __restrict__ normAB,
                                                    float* __restrict__ Cw){
  __shared__ float tile[16][128];
  __shared__ cf tw[128];
  init_tw(tw, 128, -1.f);
  int n = blockIdx.x, h0 = blockIdx.y*16;
  float A = normAB[n*2], Bc = normAB[n*2+1];
  for (int i=threadIdx.x;i<2048;i+=256) tile[i>>7][i&127] = fmaf(x[n*16384 + h0*128 + i], A, Bc);
  __syncthreads();
  for (int i=threadIdx.x;i<1024;i+=256){
    int hl=i>>6, w=i&63;
    float a=tile[hl][w], b=tile[hl][w+64];
    tile[hl][w]=a+b; tile[hl][w+64]=a-b;
  }
  __syncthreads();
  int hl = threadIdx.x >> 4, kws = threadIdx.x & 15;
  for (int kw=kws; kw<33; kw+=16){
    int sel = (kw&1)? 64 : 0;
    float re=0.f, im=0.f; int idx=0;
    for (int w=0;w<64;++w){
      float v=tile[hl][sel+w]; cf t=tw[idx];
      re=fmaf(v,t.x,re); im=fmaf(v,t.y,im);
      idx=(idx+kw)&127;
    }
    float* d = Cw + (((n*128)+(h0+hl))*33 + kw)*2;
    d[0]=re*(1.f/16384.f); d[1]=im*(1.f/16384.f);
  }
}

// truncated col DFT with radix-2 on h: F[n][r][kw]; grid (64,9)
__global__ __launch_bounds__(256) void k_fcol(const float* __restrict__ Cw, float* __restrict__ F){
  __shared__ cf col[4][128];
  __shared__ cf tw[128];
  init_tw(tw, 128, -1.f);
  int n = blockIdx.x, kwb = blockIdx.y*4;
  for (int i=threadIdx.x;i<512;i+=256){
    int kwl=i>>7, h=i&127; int kw=kwb+kwl;
    col[kwl][h] = (kw<33) ? ldc(Cw + ((n*128+h)*33+kw)*2) : make_float2(0.f,0.f);
  }
  __syncthreads();
  {
    int i = threadIdx.x;
    int kwl = i>>6, h = i&63;
    cf a = col[kwl][h], b = col[kwl][h+64];
    col[kwl][h]    = make_float2(a.x+b.x, a.y+b.y);
    col[kwl][h+64] = make_float2(a.x-b.x, a.y-b.y);
  }
  __syncthreads();
  int r = threadIdx.x & 63, kwl = threadIdx.x >> 6;
  int kw = kwb + kwl;
  if (kw >= 33) return;
  int R = (r<32)? r : r+64;
  int sel = (r&1)? 64 : 0;
  float re=0.f, im=0.f; int idx=0;
  for (int j=0;j<64;++j){
    cf v=col[kwl][sel+j]; cf t=tw[idx];
    re = fmaf(v.x,t.x,re); re = fmaf(-v.y,t.y,re);
    im = fmaf(v.x,t.y,im); im = fmaf(v.y,t.x,im);
    idx=(idx+R)&127;
  }
  stc(F + ((n*64+r)*33+kw)*2, make_float2(re,im));
}

// scoreP partials; grid (32 mk, 2 b, 8 og); 4 heads share one 66-mode E tile
__global__ __launch_bounds__(256) void k_score(const float* __restrict__ F, const float* __restrict__ gam,
                                               float* __restrict__ scoreP){
  __shared__ float2 Esh[66][33];
  __shared__ float2 gsh[4][66];
  int mk = blockIdx.x, b = blockIdx.y, og = blockIdx.z;
  int m0 = mk*66;
  int t = threadIdx.x >> 3, s4 = (threadIdx.x & 7) << 2;
  for (int i = threadIdx.x; i < 2112; i += 256){
    int tt = i/66, j = i - tt*66;
    int m = m0 + j;
    int kh = m/33, kw = m - kh*33;
    const float* Fb = F + (b*32+tt)*4224;
    float2 v;
    if (kw < 32) v = *(const float2*)(Fb + (kh*33+kw)*2);
    else {
      int mh = (64-kh)&63;
      float2 a = *(const float2*)(Fb + (kh*33+32)*2);
      float2 c = *(const float2*)(Fb + (mh*33+32)*2);
      v = make_float2(0.5f*(a.x+c.x), 0.5f*(a.y-c.y));
    }
    Esh[j][tt] = v;
  }
  for (int i = threadIdx.x; i < 264; i += 256){
    int ol = i/66, j = i - ol*66;
    gsh[ol][j] = *(const float2*)(gam + ((og*4+ol)*2112 + m0 + j)*2);
  }
  __syncthreads();
  float acc[4][4];
  #pragma unroll
  for (int a=0;a<4;++a) for (int k=0;k<4;++k) acc[a][k]=0.f;
  #pragma unroll 2
  for (int j=0;j<66;++j){
    float2 et = Esh[j][t];
    float2 e0 = Esh[j][s4+0];
    float2 e1 = Esh[j][s4+1];
    float2 e2 = Esh[j][s4+2];
    float2 e3 = Esh[j][s4+3];
    #pragma unroll
    for (int ol=0;ol<4;++ol){
      float2 g = gsh[ol][j];
      float a  = g.x*et.x - g.y*et.y;
      float bb = g.x*et.y + g.y*et.x;
      acc[ol][0] = fmaf(a,e0.x,fmaf(bb,e0.y,acc[ol][0]));
      acc[ol][1] = fmaf(a,e1.x,fmaf(bb,e1.y,acc[ol][1]));
      acc[ol][2] = fmaf(a,e2.x,fmaf(bb,e2.y,acc[ol][2]));
      acc[ol][3] = fmaf(a,e3.x,fmaf(bb,e3.y,acc[ol][3]));
    }
  }
  #pragma unroll
  for (int ol=0;ol<4;++ol){
    int o = og*4+ol;
    float* sp = scoreP + (((mk*2+b)*32+o)*32 + t)*32 + s4;
    sp[0]=acc[ol][0]; sp[1]=acc[ol][1]; sp[2]=acc[ol][2]; sp[3]=acc[ol][3];
  }
}

// sum 32 partials + DC-linear terms, softmax over s -> attn
__global__ __launch_bounds__(1024) void k_softmax(float* __restrict__ attn, const float* __restrict__ F,
                                                const float* __restrict__ gcons, const float* __restrict__ scoreP){
  __shared__ float Ssh[32][33];
  int b = blockIdx.x, o = blockIdx.y;
  int t = threadIdx.x >> 5, s = threadIdx.x & 31;
  float c0=gcons[o], c1=gcons[32+o], c2=gcons[64+o];
  float sc = c0*F[(b*32+t)*4224] + c1*F[(b*32+s)*4224] + c2;
  #pragma unroll 8
  for (int p=0;p<32;++p) sc += scoreP[(((p*2+b)*32+o)*32 + t)*32 + s];
  Ssh[t][s] = sc;
  __syncthreads();
  float mx = -1e30f;
  for (int ss=0;ss<32;++ss) mx = fmaxf(mx, Ssh[t][ss]);
  float e = expf(sc - mx);
  __syncthreads();
  Ssh[t][s] = e;
  __syncthreads();
  float sum = 0.f;
  for (int ss=0;ss<32;++ss) sum += Ssh[t][ss];
  attn[(b*32+o)*1024 + t*32 + s] = e/sum;
}

__device__ __forceinline__ cf wcV_col0(const float* wV, int o, int fr){
  if (fr < 16)  return ldc(wV + ((o*16+fr)*16)*2);
  if (fr >= 112) return ldc(wV + (((32+o)*16+(fr-112))*16)*2);
  return make_float2(0.f,0.f);
}

// Pm[b,t,mh,kw] = sum_o d[o,m] * sum_s attn[b,o,t,s]*F[bs,m]; grid (2,64,4)
__global__ __launch_bounds__(256) void k_pmode(const float* __restrict__ F, const float* __restrict__ attn,
                        const float* __restrict__ wV, const float* __restrict__ wVs,
                        const float* __restrict__ wP, const float* __restrict__ wPs,
                        float* __restrict__ Pm){
  __shared__ float att[32][8][32];
  __shared__ cf Fsh[32][32];
  __shared__ cf dsh[32][32];
  int b = blockIdx.x, mh = blockIdx.y, tg = blockIdx.z;
  int fr = mh<32 ? mh : mh+64;
  int half = (mh>=32)?1:0, mr = mh&31;
  for (int i=threadIdx.x; i<8192; i+=256){
    int o = i>>8, r = i&255;
    att[o][r>>5][r&31] = attn[(b*32+o)*1024 + tg*256 + r];
  }
  for (int i=threadIdx.x; i<1024; i+=256){
    int s=i>>5, kw=i&31;
    Fsh[s][kw] = ldc(F + (((b*32+s)*64+mh)*33+kw)*2);
  }
  for (int i=threadIdx.x; i<1024; i+=256){
    int o=i>>5, kw=i&31;
    cf wp = ldc(wP + (((half*32+o)*32+mr)*32+kw)*2);
    cf bP = make_float2(wPs[o]+wp.x, wp.y);
    cf aV = make_float2(wVs[o], 0.f);
    if (kw==0){
      cf w1 = wcV_col0(wV,o,fr);
      cf w2 = wcV_col0(wV,o,(128-fr)&127);
      aV.x += 0.5f*(w1.x + w2.x);
      aV.y += 0.5f*(w1.y - w2.y);
    } else if (kw<16){
      if (fr<16){ cf wv=ldc(wV + ((o*16+fr)*16+kw)*2); aV.x+=wv.x; aV.y+=wv.y; }
      else if (fr>=112){ cf wv=ldc(wV + (((32+o)*16+(fr-112))*16+kw)*2); aV.x+=wv.x; aV.y+=wv.y; }
    }
    cf c = cmul(bP, aV);
    c.x -= wPs[o]*wVs[o];
    dsh[o][kw]=c;
  }
  __syncthreads();
  int tl = threadIdx.x>>5, kw = threadIdx.x&31;
  float ax=0.f, ay=0.f;
  for (int o=0;o<32;++o){
    float er=0.f, ei=0.f;
    #pragma unroll
    for (int s4=0;s4<32;s4+=4){
      float4 a4 = *(const float4*)&att[o][tl][s4];
      cf f0=Fsh[s4][kw], f1=Fsh[s4+1][kw], f2=Fsh[s4+2][kw], f3=Fsh[s4+3][kw];
      er=fmaf(a4.x,f0.x,er); ei=fmaf(a4.x,f0.y,ei);
      er=fmaf(a4.y,f1.x,er); ei=fmaf(a4.y,f1.y,ei);
      er=fmaf(a4.z,f2.x,er); ei=fmaf(a4.z,f2.y,ei);
      er=fmaf(a4.w,f3.x,er); ei=fmaf(a4.w,f3.y,ei);
    }
    cf d = dsh[o][kw];
    ax += d.x*er - d.y*ei;
    ay += d.x*ei + d.y*er;
  }
  int t = tg*8+tl;
  stc(Pm + ((b*32+t)*2048 + mh*32+kw)*2, make_float2(ax,ay));
}

// z = spatial A-mix of x + irfft2(Pm) + consts; stats; ALSO raw row-DFT of z
__global__ __launch_bounds__(256) void k_zmix(const float* __restrict__ x, const float* __restrict__ Pm,
                        const float* __restrict__ attn, const float* __restrict__ normAB,
                        const float* __restrict__ wVs, const float* __restrict__ wPs,
                        const float* __restrict__ wP, const float* __restrict__ bPs,
                        const float* __restrict__ bVs,
                        float* __restrict__ z, float* __restrict__ stats,
                        float* __restrict__ Tm){
  __shared__ cf Pmsh[64][33];
  __shared__ cf PmAsh[16][33];
  __shared__ float zrows[16][128];
  __shared__ float Mrow[32];
  __shared__ float cpart[33];
  __shared__ float consts;
  __shared__ cf tw[128];
  init_tw(tw, 128, 1.f);
  int n = blockIdx.x, b = n>>5, t = n&31, hb = blockIdx.y*8;
  for (int i=threadIdx.x;i<2048;i+=256)
    Pmsh[i>>5][i&31] = ldc(Pm + (n*2048 + i)*2);
  if (threadIdx.x < 32){
    int s = threadIdx.x;
    float a=0.f;
    for (int o=0;o<32;++o) a = fmaf(attn[(b*32+o)*1024 + t*32 + s], wVs[o]*wPs[o], a);
    float AxS = normAB[(b*32+s)*2], BcS = normAB[(b*32+s)*2+1];
    Mrow[s] = fmaf(a, AxS, (s==t)?1.f:0.f);
    cpart[s] = a*BcS;
  } else if (threadIdx.x == 32){
    float dcx = bPs[0];
    for (int o=0;o<32;++o){
      cf wp = ldc(wP + (o*1024)*2);
      dcx += (wPs[o]+wp.x)*bVs[o];
    }
    cpart[32] = dcx;
  }
  __syncthreads();
  if (threadIdx.x == 0){
    float c=0.f;
    for (int i=0;i<33;++i) c += cpart[i];
    consts = c;
  }
  {
    int bl = threadIdx.x>>5, kw = threadIdx.x&31;
    int h = hb + bl;
    float ser=0.f, sei=0.f, sor=0.f, soi=0.f;
    int s2h = (2*h)&127;
    int idx = 0;
    for (int khi=0;khi<32;khi+=2){
      cf v=Pmsh[khi][kw]; cf tt=tw[idx];
      ser += v.x*tt.x - v.y*tt.y; sei += v.x*tt.y + v.y*tt.x;
      idx=(idx+s2h)&127;
    }
    idx = (96*h)&127;
    for (int khi=32;khi<64;khi+=2){
      cf v=Pmsh[khi][kw]; cf tt=tw[idx];
      ser += v.x*tt.x - v.y*tt.y; sei += v.x*tt.y + v.y*tt.x;
      idx=(idx+s2h)&127;
    }
    idx = h&127;
    for (int khi=1;khi<32;khi+=2){
      cf v=Pmsh[khi][kw]; cf tt=tw[idx];
      sor += v.x*tt.x - v.y*tt.y; soi += v.x*tt.y + v.y*tt.x;
      idx=(idx+s2h)&127;
    }
    idx = (97*h)&127;
    for (int khi=33;khi<64;khi+=2){
      cf v=Pmsh[khi][kw]; cf tt=tw[idx];
      sor += v.x*tt.x - v.y*tt.y; soi += v.x*tt.y + v.y*tt.x;
      idx=(idx+s2h)&127;
    }
    PmAsh[bl][kw]   = make_float2(ser+sor, sei+soi);
    PmAsh[8+bl][kw] = make_float2(ser-sor, sei-soi);
  }
  __syncthreads();
  float cst = consts;
  float s1=0.f, s2=0.f;
  const float* xb = x + b*32*16384;
  {
    int hl = threadIdx.x>>4, wg = threadIdx.x&15;
    int w0 = wg*4;
    int gh = (hl<8)? hb+hl : hb+(hl-8)+64;
    int off = gh*128;
    float Se[4], So[4];
    #pragma unroll
    for (int j=0;j<4;++j){
      int w = w0+j;
      int s2w = (2*w)&127;
      float se=0.f, so=0.f;
      int idx=0;
      for (int kwp=0;kwp<16;++kwp){
        cf v = PmAsh[hl][2*kwp]; cf tt=tw[idx];
        float term = v.x*tt.x - v.y*tt.y;
        se += (kwp? 2.f:1.f)*term;
        idx=(idx+s2w)&127;
      }
      idx = w&127;
      for (int kwp=0;kwp<16;++kwp){
        cf v = PmAsh[hl][2*kwp+1]; cf tt=tw[idx];
        so += 2.f*(v.x*tt.x - v.y*tt.y);
        idx=(idx+s2w)&127;
      }
      Se[j]=se; So[j]=so;
    }
    float mixa[4]={0,0,0,0}, mixb[4]={0,0,0,0};
    for (int s=0;s<32;++s){
      float m = Mrow[s];
      float4 xa = *(const float4*)(xb + s*16384 + off + w0);
      float4 xc = *(const float4*)(xb + s*16384 + off + w0 + 64);
      mixa[0]=fmaf(m,xa.x,mixa[0]); mixa[1]=fmaf(m,xa.y,mixa[1]);
      mixa[2]=fmaf(m,xa.z,mixa[2]); mixa[3]=fmaf(m,xa.w,mixa[3]);
      mixb[0]=fmaf(m,xc.x,mixb[0]); mixb[1]=fmaf(m,xc.y,mixb[1]);
      mixb[2]=fmaf(m,xc.z,mixb[2]); mixb[3]=fmaf(m,xc.w,mixb[3]);
    }
    float oa[4], ob[4];
    #pragma unroll
    for (int j=0;j<4;++j){
      oa[j] = cst + Se[j] + So[j] + mixa[j];
      ob[j] = cst + Se[j] - So[j] + mixb[j];
      s1 += oa[j]+ob[j];
      s2 += oa[j]*oa[j] + ob[j]*ob[j];
      zrows[hl][w0+j]    = oa[j];
      zrows[hl][w0+64+j] = ob[j];
    }
    *(float4*)(z + n*16384 + off + w0)      = make_float4(oa[0],oa[1],oa[2],oa[3]);
    *(float4*)(z + n*16384 + off + w0 + 64) = make_float4(ob[0],ob[1],ob[2],ob[3]);
  }
  __syncthreads();
  for (int i=threadIdx.x;i<1024;i+=256){
    int hl=i>>6, w=i&63;
    float a=zrows[hl][w], bz=zrows[hl][w+64];
    zrows[hl][w]=a+bz; zrows[hl][w+64]=a-bz;
  }
  __syncthreads();
  for (int i=threadIdx.x;i<512;i+=256){
    int hl=i>>5, kw=i&31;
    int gh = (hl<8)? hb+hl : hb+(hl-8)+64;
    int sel = (kw&1)? 64 : 0;
    float re=0.f, im=0.f; int idx=0;
    for (int w=0;w<64;++w){
      float v=zrows[hl][sel+w]; cf tt=tw[idx];
      re=fmaf(v,tt.x,re); im=fmaf(v,tt.y,im);
      idx=(idx+kw)&127;
    }
    float* d = Tm + ((n*128+gh)*32+kw)*2;
    d[0]=re*(1.f/16384.f); d[1]=-im*(1.f/16384.f);
  }
  breduce2(s1,s2);
  if (threadIdx.x==0){ atomicAdd(&stats[n*2],s1); atomicAdd(&stats[n*2+1],s2); }
}

// fused fwd col DFT + weight + inverse col DFT (radix-2 both); grid (64,4)
// Also computes Parseval stats of the spatial FNO output f = irfft2(G):
//   statsF[n*2]   += 16384*Re(G[0,0])        (Σ f)
//   statsF[n*2+1] += 16384*P2                (Σ f²)
//   if do_cross: statsC[n*2] += 16384*cross  (Σ f·m0, m0 = spatial input)
__global__ __launch_bounds__(256) void k_colpair(const float* __restrict__ Tm, const float* __restrict__ wM,
                                                 const float* __restrict__ statsZ,
                                                 const float* __restrict__ ng, const float* __restrict__ nb,
                                                 int apply_an, float* __restrict__ Am,
                                                 float* __restrict__ statsF,
                                                 float* __restrict__ statsC, int do_cross){
  __shared__ cf Tsh[128][9];
  __shared__ cf Gsh[64][9];
  __shared__ cf Msh[64][9];
  __shared__ cf tw[128];
  init_tw(tw,128,-1.f);
  int n = blockIdx.x, kw8 = blockIdx.y*8;
  float C1 = 1.f, Dc128 = 0.f;
  if (apply_an){
    float S=statsZ[n*2], S2=statsZ[n*2+1];
    float mz=S*(1.f/16384.f), vz=S2*(1.f/16384.f)-mz*mz;
    float az=rsqrtf(vz+EPSV);
    float g1=ng[1], g2=ng[2];
    float vat = g1*g1*vz*az*az;
    C1 = az*g1*rsqrtf(vat+EPSV)*g2;
    Dc128 = (nb[2] - mz*C1)*(1.f/128.f);
  }
  for (int i=threadIdx.x;i<1024;i+=256){
    int h=i>>3, kwl=i&7;
    cf v = ldc(Tm + ((n*128+h)*32 + kw8+kwl)*2);
    v.x *= C1; v.y *= C1;
    if (apply_an && (kw8+kwl)==0) v.x += Dc128;
    Tsh[h][kwl] = v;
  }
  __syncthreads();
  for (int i=threadIdx.x;i<512;i+=256){
    int h=i>>3, kwl=i&7;
    cf a=Tsh[h][kwl], b=Tsh[h+64][kwl];
    Tsh[h][kwl]    = make_float2(a.x+b.x, a.y+b.y);
    Tsh[h+64][kwl] = make_float2(a.x-b.x, a.y-b.y);
  }
  __syncthreads();
  {
    int kwl = threadIdx.x&7, base = threadIdx.x>>3;
    for (int r=0;r<2;++r){
      int khi = r*32 + base;
      int khF = (khi<32)? khi : khi+64;
      int sel = (khi&1)? 64 : 0;
      float re=0.f, im=0.f; int idx=0;
      for (int j=0;j<64;++j){
        cf v=Tsh[sel+j][kwl]; cf t=tw[idx];
        re += v.x*t.x - v.y*t.y; im += v.x*t.y + v.y*t.x;
        idx=(idx+khF)&127;
      }
      int half=(khi>=32)?1:0, mr=khi&31;
      cf wv = ldc(wM + ((half*32+mr)*32 + kw8+kwl)*2);
      Msh[khi][kwl] = make_float2(re,im);
      Gsh[khi][kwl] = cmul(make_float2(re,im), wv);
    }
  }
  __syncthreads();
  {
    int kwl = threadIdx.x&7, base = threadIdx.x>>3;
    for (int r=0;r<2;++r){
      int h = r*32 + base;
      float ser=0.f, sei=0.f, sor=0.f, soi=0.f;
      int s2h = (2*h)&127;
      int idx=0;
      for (int khi=0;khi<32;khi+=2){
        cf v=Gsh[khi][kwl]; cf t=tw[idx];
        ser += v.x*t.x + v.y*t.y; sei += v.y*t.x - v.x*t.y;
        idx=(idx+s2h)&127;
      }
      idx=(96*h)&127;
      for (int khi=32;khi<64;khi+=2){
        cf v=Gsh[khi][kwl]; cf t=tw[idx];
        ser += v.x*t.x + v.y*t.y; sei += v.y*t.x - v.x*t.y;
        idx=(idx+s2h)&127;
      }
      idx=h&127;
      for (int khi=1;khi<32;khi+=2){
        cf v=Gsh[khi][kwl]; cf t=tw[idx];
        sor += v.x*t.x + v.y*t.y; soi += v.y*t.x - v.x*t.y;
        idx=(idx+s2h)&127;
      }
      idx=(97*h)&127;
      for (int khi=33;khi<64;khi+=2){
        cf v=Gsh[khi][kwl]; cf t=tw[idx];
        sor += v.x*t.x + v.y*t.y; soi += v.y*t.x - v.x*t.y;
        idx=(idx+s2h)&127;
      }
      stc(Am + ((n*128+h)*32 + kw8+kwl)*2,    make_float2(ser+sor, sei+soi));
      stc(Am + ((n*128+h+64)*32 + kw8+kwl)*2, make_float2(ser-sor, sei-soi));
    }
  }
  // ---- Parseval stats ----
  float p2=0.f, cx=0.f;
  for (int i=threadIdx.x;i<512;i+=256){
    int khi=i>>3, kwl=i&7;
    int kw=kw8+kwl;
    if (kw>=1){
      cf g=Gsh[khi][kwl];
      p2 += 2.f*(g.x*g.x+g.y*g.y);
      if (do_cross){ cf m=Msh[khi][kwl]; cx += 2.f*(g.x*m.x+g.y*m.y); }
    }
  }
  if (kw8==0){
    int tid=threadIdx.x;
    if (tid==0){
      cf g0=Gsh[0][0];
      p2 += g0.x*g0.x;
      if (do_cross) cx += g0.x*Msh[0][0].x;
      atomicAdd(&statsF[n*2], 16384.f*g0.x);
    } else if (tid<32){
      cf a=Gsh[tid][0], b=Gsh[64-tid][0];
      float fex=0.5f*(a.x+b.x), fey=0.5f*(a.y-b.y);
      p2 += 2.f*(fex*fex+fey*fey);
      if (do_cross){ cf m=Msh[tid][0]; cx += 2.f*(fex*m.x+fey*m.y); }
    } else if (tid==32){
      cf v=Gsh[32][0];
      p2 += 0.5f*(v.x*v.x+v.y*v.y);
      if (do_cross){
        // M0hat at kh=32 (even kh uses post-butterfly sum part): sum u[j]*(-i)^j
        float mr=0.f, mi=0.f;
        for (int j=0;j<64;++j){
          cf u=Tsh[j][0];
          int q=j&3;
          if (q==0){ mr+=u.x; mi+=u.y; }
          else if (q==1){ mr+=u.y; mi-=u.x; }
          else if (q==2){ mr-=u.x; mi-=u.y; }
          else        { mr-=u.y; mi+=u.x; }
        }
        cx += v.x*mr + v.y*mi;
      }
    }
  }
  breduce2(p2,cx);
  if (threadIdx.x==0){
    atomicAdd(&statsF[n*2+1], 16384.f*p2);
    if (do_cross) atomicAdd(&statsC[n*2], 16384.f*cx);
  }
}

// fused irow(f0) + gelu-mix + statsM0 + row-DFT of m0 -> Tm; grid (64,8)
__global__ __launch_bounds__(256) void k_m0_irow(const float* __restrict__ Am, const float* __restrict__ z,
                              const float* __restrict__ stats0, const float* __restrict__ statsZ,
                              const float* __restrict__ ng, const float* __restrict__ nb,
                              const float* __restrict__ wM0s, const float* __restrict__ bM0s,
                              float* __restrict__ m0out, float* __restrict__ Tm,
                              float* __restrict__ statsM0){
  __shared__ cf rowA[16][33];
  __shared__ float tile[16][128];
  __shared__ cf tw[128];
  init_tw(tw,128,1.f);
  int n=blockIdx.x, h0=blockIdx.y*16;
  for (int i=threadIdx.x;i<512;i+=256){
    int hl=i>>5, kw=i&31;
    rowA[hl][kw] = ldc(Am + ((n*128+h0+hl)*32+kw)*2);
  }
  float S0=stats0[n*2], S02=stats0[n*2+1];
  float m0m=S0*(1.f/16384.f), v0=S02*(1.f/16384.f)-m0m*m0m;
  float A0=rsqrtf(v0+EPSV)*ng[3];
  float B0=nb[3]-m0m*A0;
  float Sz=statsZ[n*2], Sz2=statsZ[n*2+1];
  float mz=Sz*(1.f/16384.f), vz=Sz2*(1.f/16384.f)-mz*mz;
  float az=rsqrtf(vz+EPSV);
  float g1=ng[1], g2=ng[2];
  float vat=g1*g1*vz*az*az;
  float C1=az*g1*rsqrtf(vat+EPSV)*g2;
  float Dc=nb[2]-mz*C1;
  float ws_=wM0s[0], bs_=bM0s[0];
  __syncthreads();
  float sm=0.f, sm2=0.f;
  for (int i=threadIdx.x;i<1024;i+=256){
    int hl=i>>6, w=i&63;
    int s2w = (2*w)&127;
    float se=0.f, so=0.f;
    int idx=0;
    for (int kwp=0;kwp<16;++kwp){
      cf v=rowA[hl][2*kwp]; cf t=tw[idx];
      float term=v.x*t.x-v.y*t.y;
      se += (kwp? 2.f:1.f)*term;
      idx=(idx+s2w)&127;
    }
    idx = w&127;
    for (int kwp=0;kwp<16;++kwp){
      cf v=rowA[hl][2*kwp+1]; cf t=tw[idx];
      so += 2.f*(v.x*t.x-v.y*t.y);
      idx=(idx+s2w)&127;
    }
    float oa = se+so, ob = se-so;
    int gi = n*16384+(h0+hl)*128+w;
    float an_a = fmaf(z[gi],C1,Dc);
    float pre_a = fmaf(oa,A0,B0) + fmaf(ws_,an_a,bs_);
    float ga = 0.5f*pre_a*(1.f+erff(pre_a*0.70710678118654752f));
    m0out[gi]=ga; tile[hl][w]=ga;
    float an_b = fmaf(z[gi+64],C1,Dc);
    float pre_b = fmaf(ob,A0,B0) + fmaf(ws_,an_b,bs_);
    float gb = 0.5f*pre_b*(1.f+erff(pre_b*0.70710678118654752f));
    m0out[gi+64]=gb; tile[hl][w+64]=gb;
    sm += ga+gb; sm2 += ga*ga + gb*gb;
  }
  __syncthreads();
  for (int i=threadIdx.x;i<1024;i+=256){
    int hl=i>>6, w=i&63;
    float a=tile[hl][w], b=tile[hl][w+64];
    tile[hl][w]=a+b; tile[hl][w+64]=a-b;
  }
  __syncthreads();
  // row-DFT with +1 twiddles on real input: im negated at store
  for (int i=threadIdx.x;i<512;i+=256){
    int hl=i>>5, kw=i&31;
    int sel = (kw&1)? 64:0;
    float re=0.f,im=0.f; int idx=0;
    for (int w=0;w<64;++w){
      float v=tile[hl][sel+w]; cf t=tw[idx];
      re=fmaf(v,t.x,re); im=fmaf(v,t.y,im);
      idx=(idx+kw)&127;
    }
    float* d = Tm + ((n*128+h0+hl)*32+kw)*2;
    d[0]=re*(1.f/16384.f); d[1]=-im*(1.f/16384.f);
  }
  breduce2(sm,sm2);
  if (threadIdx.x==0){ atomicAdd(&statsM0[n*2],sm); atomicAdd(&statsM0[n*2+1],sm2); }
}

// fused irow(f1) + closed-form m1 + attention residual -> out; grid (64,8)
__global__ __launch_bounds__(256) void k_final_irow(const float* __restrict__ Am, const float* __restrict__ m0,
                        const float* __restrict__ z,
                        const float* __restrict__ stats1, const float* __restrict__ statsM0,
                        const float* __restrict__ statsC, const float* __restrict__ statsZ,
                        const float* __restrict__ ng, const float* __restrict__ nb,
                        const float* __restrict__ wM1s, const float* __restrict__ bM1s,
                        float* __restrict__ out){
  __shared__ cf rowA[16][33];
  __shared__ cf tw[128];
  init_tw(tw,128,1.f);
  int n=blockIdx.x, h0=blockIdx.y*16;
  for (int i=threadIdx.x;i<512;i+=256){
    int hl=i>>5, kw=i&31;
    rowA[hl][kw] = ldc(Am + ((n*128+h0+hl)*32+kw)*2);
  }
  const float N = 16384.f, iN = 1.f/16384.f;
  float Sf=stats1[n*2], Sf2=stats1[n*2+1];
  float m1m=Sf*iN, v1=Sf2*iN-m1m*m1m;
  float A1=rsqrtf(v1+EPSV)*ng[4];
  float Bc1=nb[4]-m1m*A1;
  float ws_=wM1s[0], K=Bc1+bM1s[0];
  float Sm=statsM0[n*2], Sm2=statsM0[n*2+1], Sfm=statsC[n*2];
  float S1m = A1*Sf + ws_*Sm + N*K;
  float S2m = A1*A1*Sf2 + ws_*ws_*Sm2 + N*K*K + 2.f*A1*ws_*Sfm + 2.f*A1*K*Sf + 2.f*ws_*K*Sm;
  float mean2 = S1m*iN, var2 = S2m*iN - mean2*mean2;
  float A2=rsqrtf(var2+EPSV)*ng[5];
  float B2c=nb[5]-mean2*A2;
  float Sz=statsZ[n*2], Sz2=statsZ[n*2+1];
  float mz=Sz*iN, vz=Sz2*iN-mz*mz;
  float Az=rsqrtf(vz+EPSV)*ng[1];
  float Bz=nb[1]-mz*Az;
  float cf1 = A2*A1, cm0 = A2*ws_, cc = A2*K + B2c;
  __syncthreads();
  for (int i=threadIdx.x;i<1024;i+=256){
    int hl=i>>6, w=i&63;
    int s2w = (2*w)&127;
    float se=0.f, so=0.f;
    int idx=0;
    for (int kwp=0;kwp<16;++kwp){
      cf v=rowA[hl][2*kwp]; cf t=tw[idx];
      float term=v.x*t.x-v.y*t.y;
      se += (kwp? 2.f:1.f)*term;
      idx=(idx+s2w)&127;
    }
    idx = w&127;
    for (int kwp=0;kwp<16;++kwp){
      cf v=rowA[hl][2*kwp+1]; cf t=tw[idx];
      so += 2.f*(v.x*t.x-v.y*t.y);
      idx=(idx+s2w)&127;
    }
    float oa = se+so, ob = se-so;
    int gi = n*16384+(h0+hl)*128+w;
    out[gi]    = fmaf(oa,cf1, fmaf(m0[gi],cm0, cc)) + fmaf(z[gi],Az,Bz);
    out[gi+64] = fmaf(ob,cf1, fmaf(m0[gi+64],cm0, cc)) + fmaf(z[gi+64],Az,Bz);
  }
}

// ---------------------------------------------------------------------------
extern "C" void kernel_launch(void* const* d_in, const int* in_sizes, int n_in,
                              void* d_out, int out_size, void* d_ws, size_t ws_size,
                              hipStream_t stream){
  (void)in_sizes; (void)n_in; (void)out_size; (void)ws_size;
  const float* x   = (const float*)d_in[0];
  const float* wK  = (const float*)d_in[1];
  const float* wKs = (const float*)d_in[2];
  const float* bKs = (const float*)d_in[3];
  const float* wQ  = (const float*)d_in[4];
  const float* wQs = (const float*)d_in[5];
  const float* bQs = (const float*)d_in[6];
  const float* wV  = (const float*)d_in[7];
  const float* wVs = (const float*)d_in[8];
  const float* bVs = (const float*)d_in[9];
  const float* wP  = (const float*)d_in[10];
  const float* wPs = (const float*)d_in[11];
  const float* bPs = (const float*)d_in[12];
  const float* wM0 = (const float*)d_in[13];
  const float* wM0s= (const float*)d_in[14];
  const float* bM0s= (const float*)d_in[15];
  const float* wM1 = (const float*)d_in[16];
  const float* wM1s= (const float*)d_in[17];
  const float* bM1s= (const float*)d_in[18];
  const float* ng  = (const float*)d_in[19];
  const float* nb  = (const float*)d_in[20];
  float* out = (float*)d_out;
  float* ws  = (float*)d_ws;

  float* F      = ws;                     //   270,336
  float* Cw     = F + 270336;             //   540,672
  float* scoreP = Cw + 540672;            // 2,097,152
  float* attn   = scoreP + 2097152;       //    65,536
  float* stats  = attn + 65536;           //       640 (zeroed by k_gamma)
  float* Pm     = stats + 640;            //   262,144
  float* gcons  = Pm + 262144;            //       128
  float* gam    = gcons + 128;            //   135,168
  float* normAB = gam + 135168;           //       128
  float* z      = normAB + 128;           // 1,048,576
  float* m0b    = z + 1048576;            // 1,048,576
  float* Tm     = m0b + 1048576;          //   524,288
  float* Am     = Tm + 524288;            //   524,288
  float* statsZ = stats;
  float* stats0 = stats + 128;
  float* stats1 = stats + 256;
  float* statsM0= stats + 384;
  float* statsC = stats + 512;

  k_gamma_xstats<<<96,256,0,stream>>>(wQ,wQs,bQs, wK,wKs,bKs, x, ng, nb, gam, gcons, stats, normAB);
  k_rfft_row_x<<<dim3(64,8),256,0,stream>>>(x, normAB, Cw);
  k_fcol<<<dim3(64,9),256,0,stream>>>(Cw, F);
  k_score<<<dim3(32,2,8),256,0,stream>>>(F, gam, scoreP);
  k_softmax<<<dim3(2,32),1024,0,stream>>>(attn, F, gcons, scoreP);
  k_pmode<<<dim3(2,64,4),256,0,stream>>>(F, attn, wV, wVs, wP, wPs, Pm);
  k_zmix<<<dim3(64,8),256,0,stream>>>(x, Pm, attn, normAB, wVs, wPs, wP, bPs, bVs, z, statsZ, Tm);
  k_colpair<<<dim3(64,4),256,0,stream>>>(Tm, wM0, statsZ, ng, nb, 1, Am, stats0, (float*)nullptr, 0);
  k_m0_irow<<<dim3(64,8),256,0,stream>>>(Am, z, stats0, statsZ, ng, nb, wM0s, bM0s, m0b, Tm, statsM0);
  k_colpair<<<dim3(64,4),256,0,stream>>>(Tm, wM1, statsZ, ng, nb, 0, Am, stats1, statsC, 1);
  k_final_irow<<<dim3(64,8),256,0,stream>>>(Am, m0b, z, stats1, statsM0, statsC, statsZ, ng, nb, wM1s, bM1s, out);
}